// Round 14
// baseline (392.612 us; speedup 1.0000x reference)
//
#include <hip/hip_runtime.h>

#define D_   256
#define UD_  48
#define NO_  80
#define T_   128
#define B_   2048

typedef __bf16 bf16x8 __attribute__((ext_vector_type(8)));
typedef float  f32x4  __attribute__((ext_vector_type(4)));
typedef unsigned short ushort_t;

static __device__ __forceinline__ ushort_t f2bf(float f){
  return __builtin_bit_cast(ushort_t, (__bf16)f);
}
static __device__ __forceinline__ float bf2f(ushort_t u){
  union { unsigned int i; float f; } c; c.i = ((unsigned int)u) << 16; return c.f;
}
static __device__ __forceinline__ f32x4 mfma16(bf16x8 a, bf16x8 b, f32x4 c){
  return __builtin_amdgcn_mfma_f32_16x16x32_bf16(a, b, c, 0, 0, 0);
}

// ---------------- prep: closed-form 2-NS polynomial (r12 chain, verified exact) ----------
// Vinv ~= q(V), q(v)=8-28v+56v^2-70v^3+56v^4-28v^5+8v^6-v^7; 1-v q(v) = (1-v)^8.

// W = V@V (blocks 0..255) | Cw = C@V (256..335) | lam,dVd (336)
__global__ void __launch_bounds__(256) k1(
    const float* __restrict__ V, const float* __restrict__ eig,
    const float* __restrict__ Cmat,
    float* __restrict__ W, float* __restrict__ Cw,
    float* __restrict__ lam, float* __restrict__ dVd){
  const int bid = blockIdx.x, tid = threadIdx.x;
  if (bid < 256){
    const float* Ar = V + bid*D_;
    float a0=0.f,a1=0.f,a2=0.f,a3=0.f;
    #pragma unroll 4
    for (int k = 0; k < D_; k += 4){
      a0 += Ar[k+0] * V[(k+0)*D_ + tid];
      a1 += Ar[k+1] * V[(k+1)*D_ + tid];
      a2 += Ar[k+2] * V[(k+2)*D_ + tid];
      a3 += Ar[k+3] * V[(k+3)*D_ + tid];
    }
    W[bid*D_ + tid] = (a0+a1)+(a2+a3);
  } else if (bid < 256 + NO_){
    const int n = bid - 256;
    float acc = 0.f;
    #pragma unroll 4
    for (int j = 0; j < D_; ++j) acc += Cmat[n*D_ + j] * V[j*D_ + tid];
    Cw[n*D_ + tid] = acc;
  } else {
    lam[tid] = 0.99f / (1.0f + expf(-eig[tid]));
    const float v = V[tid*D_ + tid];
    dVd[tid] = v - bf2f(f2bf(v));
  }
}

// V3 = V@W (blocks 0..255) | V4 = W@W (blocks 256..511)
__global__ void __launch_bounds__(256) k2(
    const float* __restrict__ V, const float* __restrict__ W,
    float* __restrict__ V3, float* __restrict__ V4){
  const int bid = blockIdx.x, tid = threadIdx.x;
  const int i = bid & 255;
  const float* Ar = (bid < 256 ? V : W) + i*D_;
  float a0=0.f,a1=0.f,a2=0.f,a3=0.f;
  #pragma unroll 4
  for (int k = 0; k < D_; k += 4){
    a0 += Ar[k+0] * W[(k+0)*D_ + tid];
    a1 += Ar[k+1] * W[(k+1)*D_ + tid];
    a2 += Ar[k+2] * W[(k+2)*D_ + tid];
    a3 += Ar[k+3] * W[(k+3)*D_ + tid];
  }
  float* dst = (bid < 256) ? V3 : V4;
  dst[i*D_ + tid] = (a0+a1)+(a2+a3);
}

// X2 = [8I -28V +56W -70V3 +56V4] + V4 @ (-28V +8W -V3); writes VinvT + Lw.
__global__ void __launch_bounds__(256) k3(
    const float* __restrict__ V, const float* __restrict__ W,
    const float* __restrict__ V3, const float* __restrict__ V4,
    const float* __restrict__ Lmat, const float* __restrict__ dt,
    float* __restrict__ VinvT, float* __restrict__ Lw){
  __shared__ float row[256];
  const int i = blockIdx.x, j = threadIdx.x;
  const float* r4 = V4 + i*D_;
  float a0=0.f,a1=0.f,a2=0.f,a3=0.f;
  #pragma unroll 4
  for (int k = 0; k < D_; k += 4){
    a0 += r4[k+0] * (-28.f*V[(k+0)*D_+j] + 8.f*W[(k+0)*D_+j] - V3[(k+0)*D_+j]);
    a1 += r4[k+1] * (-28.f*V[(k+1)*D_+j] + 8.f*W[(k+1)*D_+j] - V3[(k+1)*D_+j]);
    a2 += r4[k+2] * (-28.f*V[(k+2)*D_+j] + 8.f*W[(k+2)*D_+j] - V3[(k+2)*D_+j]);
    a3 += r4[k+3] * (-28.f*V[(k+3)*D_+j] + 8.f*W[(k+3)*D_+j] - V3[(k+3)*D_+j]);
  }
  const float out = (i == j ? 8.f : 0.f)
                  - 28.f*V[i*D_+j] + 56.f*W[i*D_+j] - 70.f*V3[i*D_+j] + 56.f*V4[i*D_+j]
                  + ((a0+a1)+(a2+a3));
  VinvT[j*D_ + i] = out;
  row[j] = out;
  __syncthreads();
  if (j < UD_){
    float acc = 0.f;
    #pragma unroll 4
    for (int k = 0; k < D_; ++k) acc += row[k] * Lmat[k*UD_ + j];
    Lw[i*UD_ + j] = acc * dt[0];
  }
}

// w0 = z0@VinvT (blocks 0..255) | Lws pack (256..287) | packA (288..341)
__global__ void __launch_bounds__(256) k_prep2(
    const float* __restrict__ z0, const float* __restrict__ VinvT,
    const float* __restrict__ Lw, const float* __restrict__ V,
    const float* __restrict__ Cw, const float* __restrict__ Dmat,
    const float* __restrict__ dt,
    ushort_t* __restrict__ Wchk, ushort_t* __restrict__ Lws,
    ushort_t* __restrict__ Af){
  __shared__ float zr[8][256];
  const int bid = blockIdx.x, tid = threadIdx.x;
  if (bid < 256){
    const int b0 = bid * 8;
    #pragma unroll
    for (int r = 0; r < 8; ++r) zr[r][tid] = z0[(size_t)(b0+r)*D_ + tid];
    __syncthreads();
    float acc[8] = {0.f,0.f,0.f,0.f,0.f,0.f,0.f,0.f};
    #pragma unroll 4
    for (int j = 0; j < D_; ++j){
      const float vj = VinvT[j*D_ + tid];
      #pragma unroll
      for (int r = 0; r < 8; ++r) acc[r] += zr[r][j] * vj;
    }
    #pragma unroll
    for (int r = 0; r < 8; ++r)
      Wchk[(size_t)(b0+r)*D_ + tid] = f2bf(acc[r]);
  } else if (bid < 288){
    const int f = bid - 256;
    if (tid < 64){
      const int l = tid, lm = l & 15, lh = l >> 4;
      const int it = f >> 1, kc2 = f & 1;
      const int ig = it*16 + lm;
      #pragma unroll
      for (int j = 0; j < 8; ++j){
        const int k = 32*kc2 + 4*lh + (j & 3) + 16*(j >> 2);
        Lws[(f*64 + l)*8 + j] = f2bf(k < UD_ ? Lw[ig*UD_ + k] : 0.f);
      }
    }
  } else {
    const int v = (bid - 288)*4 + (tid >> 6);
    if (v < 210){
      const int mt = v / 10, kc = v % 10;
      const int l = tid & 63, lm = l & 15, lh = l >> 4;
      const float dts = dt[0];
      #pragma unroll
      for (int j = 0; j < 8; ++j){
        const int k = 32*kc + 4*lh + (j & 3) + 16*(j >> 2);
        float val = 0.f;
        if (mt < 16){
          if (kc < 8) val = V[(mt*16 + lm)*D_ + k];
        } else {
          const int n = (mt - 16)*16 + lm;
          if (kc < 8) val = Cw[n*D_ + k];
          else { const int ku = k - 256; if (ku < UD_) val = dts * Dmat[n*UD_ + ku]; }
        }
        Af[((size_t)(mt*10 + kc)*64 + l)*8 + j] = f2bf(val);
      }
    }
  }
}

// ---------------- parallel local-chunk scan (phase A) ----------------
#define LSCAN_STEP(UA, UB, UC) do {                                             \
  union { ushort_t us[8]; bf16x8 v; } c0, c1;                                   \
  c0.us[0]=f2bf((UA).x); c0.us[1]=f2bf((UA).y); c0.us[2]=f2bf((UA).z); c0.us[3]=f2bf((UA).w); \
  c0.us[4]=f2bf((UB).x); c0.us[5]=f2bf((UB).y); c0.us[6]=f2bf((UB).z); c0.us[7]=f2bf((UB).w); \
  c1.us[0]=f2bf((UC).x); c1.us[1]=f2bf((UC).y); c1.us[2]=f2bf((UC).z); c1.us[3]=f2bf((UC).w); \
  c1.us[4]=0; c1.us[5]=0; c1.us[6]=0; c1.us[7]=0;                               \
  _Pragma("unroll")                                                             \
  for (int q = 0; q < 4; ++q){                                                  \
    f32x4 acc = {0.f,0.f,0.f,0.f};                                              \
    acc = mfma16(lwf[q*2+0], c0.v, acc);                                        \
    acc = mfma16(lwf[q*2+1], c1.v, acc);                                        \
    _Pragma("unroll")                                                           \
    for (int r = 0; r < 4; ++r) w[q*4+r] = lamr[q*4+r]*w[q*4+r] + acc[r];       \
  }                                                                             \
} while(0)

// 1920 blocks = 15 ch x 128 bq; chunk ch's local 8-step scan from zero state;
// writes raw c_ch into Wchk slot ch+1 (bf16). (Prefix combine happens in k_fused.)
__global__ void __launch_bounds__(256) k_scanA(const float* __restrict__ U,
    const ushort_t* __restrict__ Lws, const float* __restrict__ lam,
    ushort_t* __restrict__ Wchk){
  const int tid = threadIdx.x;
  const int wid = tid >> 6, l = tid & 63;
  const int lm = l & 15, lh = l >> 4;
  const int ch = blockIdx.x >> 7;        // 0..14
  const int bq = blockIdx.x & 127;
  const int row = bq*16 + lm;
  const int itb = wid*4;

  bf16x8 lwf[8];
  #pragma unroll
  for (int q = 0; q < 4; ++q)
    #pragma unroll
    for (int c = 0; c < 2; ++c)
      lwf[q*2 + c] = *(const bf16x8*)(Lws + ((size_t)(((itb+q)*2 + c)*64 + l))*8);

  float lamr[16], w[16];
  #pragma unroll
  for (int q = 0; q < 4; ++q){
    const int i = (itb+q)*16 + 4*lh;
    const float4 lv = *(const float4*)&lam[i];
    lamr[q*4+0]=lv.x; lamr[q*4+1]=lv.y; lamr[q*4+2]=lv.z; lamr[q*4+3]=lv.w;
    w[q*4+0]=0.f; w[q*4+1]=0.f; w[q*4+2]=0.f; w[q*4+3]=0.f;
  }

  const size_t TS = (size_t)B_ * UD_;
  const float* Urow = U + ((size_t)(ch*8)*B_ + row) * UD_;
  float4 Aa, Ab, Ac, Ba, Bb, Bc;
  Aa = *(const float4*)&Urow[4*lh]; Ab = *(const float4*)&Urow[16+4*lh]; Ac = *(const float4*)&Urow[32+4*lh];
  { const float* Up = Urow + TS;
    Ba = *(const float4*)&Up[4*lh]; Bb = *(const float4*)&Up[16+4*lh]; Bc = *(const float4*)&Up[32+4*lh]; }

  #pragma unroll
  for (int tt = 0; tt < 4; ++tt){
    LSCAN_STEP(Aa, Ab, Ac);
    if (tt < 3){
      const float* Up = Urow + (size_t)(2*tt+2)*TS;
      Aa = *(const float4*)&Up[4*lh]; Ab = *(const float4*)&Up[16+4*lh]; Ac = *(const float4*)&Up[32+4*lh];
    }
    LSCAN_STEP(Ba, Bb, Bc);
    if (tt < 3){
      const float* Up = Urow + (size_t)(2*tt+3)*TS;
      Ba = *(const float4*)&Up[4*lh]; Bb = *(const float4*)&Up[16+4*lh]; Bc = *(const float4*)&Up[32+4*lh];
    }
  }
  #pragma unroll
  for (int q = 0; q < 4; ++q){
    const int i = (itb+q)*16 + 4*lh;
    ushort4 o; o.x=f2bf(w[q*4+0]); o.y=f2bf(w[q*4+1]); o.z=f2bf(w[q*4+2]); o.w=f2bf(w[q*4+3]);
    *(ushort4*)(Wchk + ((size_t)(ch+1)*B_ + row)*D_ + i) = o;
  }
}

// ---------------- fused: prefix combine + replay + output GEMM ----------------
// r13 structure + two changes:
// (1) XCD-pairing swizzle: dispatcher round-robins consecutive blocks across the
//     8 XCDs, so r6's h-in-low-bit NEVER actually co-located h0/h1 pairs. Now h
//     is bit 3: pair members are 8 apart -> same XCD slot -> shared U/Wchk in L2.
// (2) scanB merged, register-light: lam^8 computed ON THE FLY (no l8v[64] array --
//     r12's 256->132 VGPR collapse suspect), fold in f32 (one fewer bf16 rounding).
//     __launch_bounds__(256,1) pins the allocator at 1 wave/SIMD (512-reg budget).
__global__ void __launch_bounds__(256, 1) k_fused(
    const float* __restrict__ U, const ushort_t* __restrict__ Af,
    const ushort_t* __restrict__ Lws, const float* __restrict__ lam,
    const float* __restrict__ dVd, const ushort_t* __restrict__ Wchk,
    float* __restrict__ outZ, float* __restrict__ outY){
  __shared__ __align__(16) ushort_t AfZhL[8*8*512];   // 65536 B
  __shared__ __align__(16) ushort_t LwsL[32*512];     // 32768 B
  __shared__ __align__(16) ushort_t AfYhL[40*512];    // 40960 B
  __shared__ __align__(16) float    trbZ[4][16][68];  // 17408 B
  __shared__ __align__(16) float    dVdL[128];        // 512 B
  __shared__ __align__(16) float    lamL[256];        // 1024 B

  const int tid = threadIdx.x;
  const int d = blockIdx.x;
  const int h  = (d >> 3) & 1;                 // bit 3: pair members 8 apart
  const int pc = (d >> 4)*8 + (d & 7);         // 0..511
  const int ch = pc & 15;
  const int bq = pc >> 4;
  const int wid = tid >> 6, l = tid & 63;
  const int lm = l & 15, lh = l >> 4;
  const int col0 = bq*64 + wid*16;
  const int col = col0 + lm;

  // one-time staging
  {
    const uint4* gsrc = (const uint4*)Af;
    uint4* dz = (uint4*)AfZhL;
    #pragma unroll
    for (int r = 0; r < 16; ++r){
      const int i = r*256 + tid;
      const int f = i >> 6, l4 = i & 63;
      const int mi8 = f >> 3, kc = f & 7;
      dz[i] = gsrc[(size_t)((h*8 + mi8)*10 + kc)*64 + l4];
    }
    uint4* dy = (uint4*)AfYhL;
    const int nY = h ? 640 : 2560;
    const int sb = 16 + (h ? 4 : 0);
    #pragma unroll
    for (int r = 0; r < 10; ++r){
      const int i = r*256 + tid;
      if (i < nY){
        const int f = i >> 6, l4 = i & 63;
        const int myl = f / 10, j = f % 10;
        dy[i] = gsrc[(size_t)((sb + myl)*10 + j)*64 + l4];
      }
    }
    const uint4* ls = (const uint4*)Lws;
    uint4* ld = (uint4*)LwsL;
    #pragma unroll
    for (int r = 0; r < 8; ++r) ld[r*256 + tid] = ls[r*256 + tid];
    if (tid < 32) ((float4*)dVdL)[tid] = ((const float4*)(dVd + h*128))[tid];
    else if (tid < 96) ((float4*)lamL)[tid-32] = ((const float4*)lam)[tid-32];
  }

  // w = W_0 (slot 0)
  float w[64];
  #pragma unroll
  for (int kc = 0; kc < 8; ++kc)
    #pragma unroll
    for (int hh = 0; hh < 2; ++hh){
      const int i = 32*kc + 16*hh + 4*lh;
      const ushort4 wu = *(const ushort4*)(Wchk + (size_t)col*D_ + i);
      const int e = 8*kc + 4*hh;
      w[e+0]=bf2f(wu.x); w[e+1]=bf2f(wu.y); w[e+2]=bf2f(wu.z); w[e+3]=bf2f(wu.w);
    }

  // u prefetch
  const size_t TS = (size_t)B_ * UD_;
  const float* Ucol = U + (size_t)col * UD_;
  float4 ua, ub, uc;
  {
    const float* Ut = Ucol + (size_t)(ch*8)*TS;
    ua = *(const float4*)&Ut[4*lh]; ub = *(const float4*)&Ut[16+4*lh]; uc = *(const float4*)&Ut[32+4*lh];
  }

  __syncthreads();   // the only block-wide barrier

  // prefix combine: W_ch = fold of W_0 with c_1..c_ch; lam^8 on the fly (no array)
  #pragma unroll 1
  for (int j = 1; j <= ch; ++j){
    const ushort_t* slot = Wchk + (size_t)j*B_*D_ + (size_t)col*D_;
    #pragma unroll
    for (int kc = 0; kc < 8; ++kc)
      #pragma unroll
      for (int hh = 0; hh < 2; ++hh){
        const int i = 32*kc + 16*hh + 4*lh;
        const ushort4 cu = *(const ushort4*)(slot + i);
        const float4 lv = *(const float4*)&lamL[i];
        const int e = 8*kc + 4*hh;
        float t;
        t = lv.x*lv.x; t = t*t; t = t*t; w[e+0] = t*w[e+0] + bf2f(cu.x);
        t = lv.y*lv.y; t = t*t; t = t*t; w[e+1] = t*w[e+1] + bf2f(cu.y);
        t = lv.z*lv.z; t = t*t; t = t*t; w[e+2] = t*w[e+2] + bf2f(cu.z);
        t = lv.w*lv.w; t = t*t; t = t*t; w[e+3] = t*w[e+3] + bf2f(cu.w);
      }
  }

#define ZLOOP(HH)                                                               \
  { float* zbase = outZ + ((size_t)t*B_ + col0)*D_ + (HH)*128;                  \
    _Pragma("unroll")                                                           \
    for (int g = 0; g < 2; ++g){                                                \
      _Pragma("unroll")                                                         \
      for (int mi = 0; mi < 4; ++mi){                                           \
        const int mi8 = g*4 + mi;                                               \
        f32x4 acc = {0.f,0.f,0.f,0.f};                                          \
        _Pragma("unroll")                                                       \
        for (int kc = 0; kc < 8; ++kc){                                         \
          const bf16x8 af = *(const bf16x8*)&AfZhL[((mi8*8+kc)*64 + l)*8];      \
          acc = mfma16(af, wfr[kc], acc);                                       \
        }                                                                       \
        const float4 dv = *(const float4*)&dVdL[mi8*16 + 4*lh];                 \
        acc[0] += dv.x * (float)wfr[((HH)*8+mi8)>>1][0 + 4*(mi8&1)];            \
        acc[1] += dv.y * (float)wfr[((HH)*8+mi8)>>1][1 + 4*(mi8&1)];            \
        acc[2] += dv.z * (float)wfr[((HH)*8+mi8)>>1][2 + 4*(mi8&1)];            \
        acc[3] += dv.w * (float)wfr[((HH)*8+mi8)>>1][3 + 4*(mi8&1)];            \
        *(float4*)&trbZ[wid][lm][mi*16 + 4*lh] = make_float4(acc[0],acc[1],acc[2],acc[3]); \
      }                                                                         \
      __builtin_amdgcn_wave_barrier();                                          \
      _Pragma("unroll")                                                         \
      for (int j = 0; j < 4; ++j){                                              \
        const int r_ = j*4 + (l >> 4), c16 = l & 15;                            \
        const float4 v = *(const float4*)&trbZ[wid][r_][4*c16];                 \
        *(float4*)&zbase[(size_t)r_*D_ + g*64 + 4*c16] = v;                     \
      }                                                                         \
      __builtin_amdgcn_wave_barrier();                                          \
    } }

#define YLOOP(COFF, NMY)                                                        \
  { float* yrow = outY + ((size_t)t*B_ + col)*NO_ + (COFF);                     \
    _Pragma("unroll")                                                           \
    for (int my = 0; my < (NMY); ++my){                                         \
      f32x4 acc = {0.f,0.f,0.f,0.f};                                            \
      _Pragma("unroll")                                                         \
      for (int kc = 0; kc < 8; ++kc){                                           \
        const bf16x8 af = *(const bf16x8*)&AfYhL[((my*10+kc)*64 + l)*8];        \
        acc = mfma16(af, wfr[kc], acc);                                         \
      }                                                                         \
      { const bf16x8 af8 = *(const bf16x8*)&AfYhL[((my*10+8)*64 + l)*8];        \
        const bf16x8 af9 = *(const bf16x8*)&AfYhL[((my*10+9)*64 + l)*8];        \
        acc = mfma16(af8, uf0, acc); acc = mfma16(af9, uf1, acc); }             \
      *(float4*)&yrow[my*16 + 4*lh] = make_float4(acc[0],acc[1],acc[2],acc[3]); \
    } }

  #pragma unroll 1
  for (int s = 0; s < 8; ++s){
    const int t = ch*8 + s;
    bf16x8 uf0, uf1;
    {
      union { ushort_t us[8]; bf16x8 v; } cv;
      cv.us[0]=f2bf(ua.x); cv.us[1]=f2bf(ua.y); cv.us[2]=f2bf(ua.z); cv.us[3]=f2bf(ua.w);
      cv.us[4]=f2bf(ub.x); cv.us[5]=f2bf(ub.y); cv.us[6]=f2bf(ub.z); cv.us[7]=f2bf(ub.w);
      uf0 = cv.v;
      cv.us[0]=f2bf(uc.x); cv.us[1]=f2bf(uc.y); cv.us[2]=f2bf(uc.z); cv.us[3]=f2bf(uc.w);
      cv.us[4]=0; cv.us[5]=0; cv.us[6]=0; cv.us[7]=0;
      uf1 = cv.v;
    }
    if (s < 7){
      const float* Ut = Ucol + (size_t)(t+1)*TS;
      ua = *(const float4*)&Ut[4*lh]; ub = *(const float4*)&Ut[16+4*lh]; uc = *(const float4*)&Ut[32+4*lh];
    }
    #pragma unroll
    for (int it = 0; it < 16; ++it){
      const bf16x8 a0 = *(const bf16x8*)&LwsL[((it*2+0)*64 + l)*8];
      const bf16x8 a1 = *(const bf16x8*)&LwsL[((it*2+1)*64 + l)*8];
      const float4 lv = *(const float4*)&lamL[32*(it>>1) + 16*(it&1) + 4*lh];
      f32x4 acc = {0.f,0.f,0.f,0.f};
      acc = mfma16(a0, uf0, acc);
      acc = mfma16(a1, uf1, acc);
      const int e0 = 8*(it>>1) + 4*(it&1);
      w[e0+0] = lv.x*w[e0+0] + acc[0];
      w[e0+1] = lv.y*w[e0+1] + acc[1];
      w[e0+2] = lv.z*w[e0+2] + acc[2];
      w[e0+3] = lv.w*w[e0+3] + acc[3];
    }
    bf16x8 wfr[8];
    #pragma unroll
    for (int kc = 0; kc < 8; ++kc){
      union { ushort_t us[8]; bf16x8 v; } cv;
      #pragma unroll
      for (int j = 0; j < 8; ++j) cv.us[j] = f2bf(w[8*kc + j]);
      wfr[kc] = cv.v;
    }
    if (h == 0){
      ZLOOP(0);
      YLOOP(0, 4);
    } else {
      ZLOOP(1);
      YLOOP(64, 1);
    }
  }
#undef ZLOOP
#undef YLOOP
}

// ---------------- launcher: 6 launches ----------------
extern "C" void kernel_launch(void* const* d_in, const int* in_sizes, int n_in,
                              void* d_out, int out_size, void* d_ws, size_t ws_size,
                              hipStream_t stream){
  const float* z0  = (const float*)d_in[0];
  const float* dt  = (const float*)d_in[2];
  const float* U   = (const float*)d_in[3];
  const float* eig = (const float*)d_in[4];
  const float* V   = (const float*)d_in[5];
  const float* L   = (const float*)d_in[6];
  const float* C   = (const float*)d_in[7];
  const float* Dm  = (const float*)d_in[8];
  float* outZ = (float*)d_out;
  float* outY = outZ + (size_t)T_*B_*D_;

  char* ws = (char*)d_ws;
  float* Wm    = (float*)(ws + 0);        // W = V^2
  float* V3m   = (float*)(ws + 262144);   // V^3
  float* VinvT = (float*)(ws + 524288);   // k3 output
  float* Lw    = (float*)(ws + 786432);
  float* Cw    = (float*)(ws + 835584);
  float* lam   = (float*)(ws + 917504);
  float* dVd   = (float*)(ws + 918528);
  ushort_t* Af   = (ushort_t*)(ws + 919552);
  ushort_t* Lws  = (ushort_t*)(ws + 1134592);
  ushort_t* Wchk = (ushort_t*)(ws + 1167360);
  // V4 parks in Wchk slot-1 space: dead after k3; scanA overwrites later (stream-ordered).
  float* V4m   = (float*)(ws + 1167360 + (size_t)B_*D_*2);
  if (ws_size < 17944576u) return;

  k1     <<<337,256,0,stream>>>(V, eig, C, Wm, Cw, lam, dVd);
  k2     <<<512,256,0,stream>>>(V, Wm, V3m, V4m);
  k3     <<<256,256,0,stream>>>(V, Wm, V3m, V4m, L, dt, VinvT, Lw);
  k_prep2<<<342,256,0,stream>>>(z0, VinvT, Lw, V, Cw, Dm, dt, Wchk, Lws, Af);
  k_scanA<<<1920,256,0,stream>>>(U, Lws, lam, Wchk);
  k_fused<<<1024,256,0,stream>>>(U, Af, Lws, lam, dVd, Wchk, outZ, outY);
}

// Round 15
// 263.627 us; speedup vs baseline: 1.4893x; 1.4893x over previous
//
#include <hip/hip_runtime.h>

#define D_   256
#define UD_  48
#define NO_  80
#define T_   128
#define B_   2048

typedef __bf16 bf16x8 __attribute__((ext_vector_type(8)));
typedef float  f32x4  __attribute__((ext_vector_type(4)));
typedef unsigned short ushort_t;

static __device__ __forceinline__ ushort_t f2bf(float f){
  return __builtin_bit_cast(ushort_t, (__bf16)f);
}
static __device__ __forceinline__ float bf2f(ushort_t u){
  union { unsigned int i; float f; } c; c.i = ((unsigned int)u) << 16; return c.f;
}
static __device__ __forceinline__ f32x4 mfma16(bf16x8 a, bf16x8 b, f32x4 c){
  return __builtin_amdgcn_mfma_f32_16x16x32_bf16(a, b, c, 0, 0, 0);
}

// ---------------- prep: closed-form 2-NS polynomial (r12 chain, verified exact) ----------
// Vinv ~= q(V), q(v)=8-28v+56v^2-70v^3+56v^4-28v^5+8v^6-v^7; 1-v q(v) = (1-v)^8.

// W = V@V (blocks 0..255) | Cw = C@V (256..335) | lam,dVd (336)
__global__ void __launch_bounds__(256) k1(
    const float* __restrict__ V, const float* __restrict__ eig,
    const float* __restrict__ Cmat,
    float* __restrict__ W, float* __restrict__ Cw,
    float* __restrict__ lam, float* __restrict__ dVd){
  const int bid = blockIdx.x, tid = threadIdx.x;
  if (bid < 256){
    const float* Ar = V + bid*D_;
    float a0=0.f,a1=0.f,a2=0.f,a3=0.f;
    #pragma unroll 4
    for (int k = 0; k < D_; k += 4){
      a0 += Ar[k+0] * V[(k+0)*D_ + tid];
      a1 += Ar[k+1] * V[(k+1)*D_ + tid];
      a2 += Ar[k+2] * V[(k+2)*D_ + tid];
      a3 += Ar[k+3] * V[(k+3)*D_ + tid];
    }
    W[bid*D_ + tid] = (a0+a1)+(a2+a3);
  } else if (bid < 256 + NO_){
    const int n = bid - 256;
    float acc = 0.f;
    #pragma unroll 4
    for (int j = 0; j < D_; ++j) acc += Cmat[n*D_ + j] * V[j*D_ + tid];
    Cw[n*D_ + tid] = acc;
  } else {
    lam[tid] = 0.99f / (1.0f + expf(-eig[tid]));
    const float v = V[tid*D_ + tid];
    dVd[tid] = v - bf2f(f2bf(v));
  }
}

// V3 = V@W (blocks 0..255) | V4 = W@W (blocks 256..511)
__global__ void __launch_bounds__(256) k2(
    const float* __restrict__ V, const float* __restrict__ W,
    float* __restrict__ V3, float* __restrict__ V4){
  const int bid = blockIdx.x, tid = threadIdx.x;
  const int i = bid & 255;
  const float* Ar = (bid < 256 ? V : W) + i*D_;
  float a0=0.f,a1=0.f,a2=0.f,a3=0.f;
  #pragma unroll 4
  for (int k = 0; k < D_; k += 4){
    a0 += Ar[k+0] * W[(k+0)*D_ + tid];
    a1 += Ar[k+1] * W[(k+1)*D_ + tid];
    a2 += Ar[k+2] * W[(k+2)*D_ + tid];
    a3 += Ar[k+3] * W[(k+3)*D_ + tid];
  }
  float* dst = (bid < 256) ? V3 : V4;
  dst[i*D_ + tid] = (a0+a1)+(a2+a3);
}

// X2 = [8I -28V +56W -70V3 +56V4] + V4 @ (-28V +8W -V3); writes VinvT + Lw.
__global__ void __launch_bounds__(256) k3(
    const float* __restrict__ V, const float* __restrict__ W,
    const float* __restrict__ V3, const float* __restrict__ V4,
    const float* __restrict__ Lmat, const float* __restrict__ dt,
    float* __restrict__ VinvT, float* __restrict__ Lw){
  __shared__ float row[256];
  const int i = blockIdx.x, j = threadIdx.x;
  const float* r4 = V4 + i*D_;
  float a0=0.f,a1=0.f,a2=0.f,a3=0.f;
  #pragma unroll 4
  for (int k = 0; k < D_; k += 4){
    a0 += r4[k+0] * (-28.f*V[(k+0)*D_+j] + 8.f*W[(k+0)*D_+j] - V3[(k+0)*D_+j]);
    a1 += r4[k+1] * (-28.f*V[(k+1)*D_+j] + 8.f*W[(k+1)*D_+j] - V3[(k+1)*D_+j]);
    a2 += r4[k+2] * (-28.f*V[(k+2)*D_+j] + 8.f*W[(k+2)*D_+j] - V3[(k+2)*D_+j]);
    a3 += r4[k+3] * (-28.f*V[(k+3)*D_+j] + 8.f*W[(k+3)*D_+j] - V3[(k+3)*D_+j]);
  }
  const float out = (i == j ? 8.f : 0.f)
                  - 28.f*V[i*D_+j] + 56.f*W[i*D_+j] - 70.f*V3[i*D_+j] + 56.f*V4[i*D_+j]
                  + ((a0+a1)+(a2+a3));
  VinvT[j*D_ + i] = out;
  row[j] = out;
  __syncthreads();
  if (j < UD_){
    float acc = 0.f;
    #pragma unroll 4
    for (int k = 0; k < D_; ++k) acc += row[k] * Lmat[k*UD_ + j];
    Lw[i*UD_ + j] = acc * dt[0];
  }
}

// w0 = z0@VinvT (blocks 0..255) | Lws pack (256..287) | packA (288..341)
__global__ void __launch_bounds__(256) k_prep2(
    const float* __restrict__ z0, const float* __restrict__ VinvT,
    const float* __restrict__ Lw, const float* __restrict__ V,
    const float* __restrict__ Cw, const float* __restrict__ Dmat,
    const float* __restrict__ dt,
    ushort_t* __restrict__ Wchk, ushort_t* __restrict__ Lws,
    ushort_t* __restrict__ Af){
  __shared__ float zr[8][256];
  const int bid = blockIdx.x, tid = threadIdx.x;
  if (bid < 256){
    const int b0 = bid * 8;
    #pragma unroll
    for (int r = 0; r < 8; ++r) zr[r][tid] = z0[(size_t)(b0+r)*D_ + tid];
    __syncthreads();
    float acc[8] = {0.f,0.f,0.f,0.f,0.f,0.f,0.f,0.f};
    #pragma unroll 4
    for (int j = 0; j < D_; ++j){
      const float vj = VinvT[j*D_ + tid];
      #pragma unroll
      for (int r = 0; r < 8; ++r) acc[r] += zr[r][j] * vj;
    }
    #pragma unroll
    for (int r = 0; r < 8; ++r)
      Wchk[(size_t)(b0+r)*D_ + tid] = f2bf(acc[r]);
  } else if (bid < 288){
    const int f = bid - 256;
    if (tid < 64){
      const int l = tid, lm = l & 15, lh = l >> 4;
      const int it = f >> 1, kc2 = f & 1;
      const int ig = it*16 + lm;
      #pragma unroll
      for (int j = 0; j < 8; ++j){
        const int k = 32*kc2 + 4*lh + (j & 3) + 16*(j >> 2);
        Lws[(f*64 + l)*8 + j] = f2bf(k < UD_ ? Lw[ig*UD_ + k] : 0.f);
      }
    }
  } else {
    const int v = (bid - 288)*4 + (tid >> 6);
    if (v < 210){
      const int mt = v / 10, kc = v % 10;
      const int l = tid & 63, lm = l & 15, lh = l >> 4;
      const float dts = dt[0];
      #pragma unroll
      for (int j = 0; j < 8; ++j){
        const int k = 32*kc + 4*lh + (j & 3) + 16*(j >> 2);
        float val = 0.f;
        if (mt < 16){
          if (kc < 8) val = V[(mt*16 + lm)*D_ + k];
        } else {
          const int n = (mt - 16)*16 + lm;
          if (kc < 8) val = Cw[n*D_ + k];
          else { const int ku = k - 256; if (ku < UD_) val = dts * Dmat[n*UD_ + ku]; }
        }
        Af[((size_t)(mt*10 + kc)*64 + l)*8 + j] = f2bf(val);
      }
    }
  }
}

// ---------------- parallel local-chunk scan (phase A) ----------------
#define LSCAN_STEP(UA, UB, UC) do {                                             \
  union { ushort_t us[8]; bf16x8 v; } c0, c1;                                   \
  c0.us[0]=f2bf((UA).x); c0.us[1]=f2bf((UA).y); c0.us[2]=f2bf((UA).z); c0.us[3]=f2bf((UA).w); \
  c0.us[4]=f2bf((UB).x); c0.us[5]=f2bf((UB).y); c0.us[6]=f2bf((UB).z); c0.us[7]=f2bf((UB).w); \
  c1.us[0]=f2bf((UC).x); c1.us[1]=f2bf((UC).y); c1.us[2]=f2bf((UC).z); c1.us[3]=f2bf((UC).w); \
  c1.us[4]=0; c1.us[5]=0; c1.us[6]=0; c1.us[7]=0;                               \
  _Pragma("unroll")                                                             \
  for (int q = 0; q < 4; ++q){                                                  \
    f32x4 acc = {0.f,0.f,0.f,0.f};                                              \
    acc = mfma16(lwf[q*2+0], c0.v, acc);                                        \
    acc = mfma16(lwf[q*2+1], c1.v, acc);                                        \
    _Pragma("unroll")                                                           \
    for (int r = 0; r < 4; ++r) w[q*4+r] = lamr[q*4+r]*w[q*4+r] + acc[r];       \
  }                                                                             \
} while(0)

// 1920 blocks = 15 ch x 128 bq; chunk ch's local 8-step scan from zero state;
// writes c_ch into Wchk slot ch+1 (bf16).
__global__ void __launch_bounds__(256) k_scanA(const float* __restrict__ U,
    const ushort_t* __restrict__ Lws, const float* __restrict__ lam,
    ushort_t* __restrict__ Wchk){
  const int tid = threadIdx.x;
  const int wid = tid >> 6, l = tid & 63;
  const int lm = l & 15, lh = l >> 4;
  const int ch = blockIdx.x >> 7;        // 0..14
  const int bq = blockIdx.x & 127;
  const int row = bq*16 + lm;
  const int itb = wid*4;

  bf16x8 lwf[8];
  #pragma unroll
  for (int q = 0; q < 4; ++q)
    #pragma unroll
    for (int c = 0; c < 2; ++c)
      lwf[q*2 + c] = *(const bf16x8*)(Lws + ((size_t)(((itb+q)*2 + c)*64 + l))*8);

  float lamr[16], w[16];
  #pragma unroll
  for (int q = 0; q < 4; ++q){
    const int i = (itb+q)*16 + 4*lh;
    const float4 lv = *(const float4*)&lam[i];
    lamr[q*4+0]=lv.x; lamr[q*4+1]=lv.y; lamr[q*4+2]=lv.z; lamr[q*4+3]=lv.w;
    w[q*4+0]=0.f; w[q*4+1]=0.f; w[q*4+2]=0.f; w[q*4+3]=0.f;
  }

  const size_t TS = (size_t)B_ * UD_;
  const float* Urow = U + ((size_t)(ch*8)*B_ + row) * UD_;
  float4 Aa, Ab, Ac, Ba, Bb, Bc;
  Aa = *(const float4*)&Urow[4*lh]; Ab = *(const float4*)&Urow[16+4*lh]; Ac = *(const float4*)&Urow[32+4*lh];
  { const float* Up = Urow + TS;
    Ba = *(const float4*)&Up[4*lh]; Bb = *(const float4*)&Up[16+4*lh]; Bc = *(const float4*)&Up[32+4*lh]; }

  #pragma unroll
  for (int tt = 0; tt < 4; ++tt){
    LSCAN_STEP(Aa, Ab, Ac);
    if (tt < 3){
      const float* Up = Urow + (size_t)(2*tt+2)*TS;
      Aa = *(const float4*)&Up[4*lh]; Ab = *(const float4*)&Up[16+4*lh]; Ac = *(const float4*)&Up[32+4*lh];
    }
    LSCAN_STEP(Ba, Bb, Bc);
    if (tt < 3){
      const float* Up = Urow + (size_t)(2*tt+3)*TS;
      Ba = *(const float4*)&Up[4*lh]; Bb = *(const float4*)&Up[16+4*lh]; Bc = *(const float4*)&Up[32+4*lh];
    }
  }
  #pragma unroll
  for (int q = 0; q < 4; ++q){
    const int i = (itb+q)*16 + 4*lh;
    ushort4 o; o.x=f2bf(w[q*4+0]); o.y=f2bf(w[q*4+1]); o.z=f2bf(w[q*4+2]); o.w=f2bf(w[q*4+3]);
    *(ushort4*)(Wchk + ((size_t)(ch+1)*B_ + row)*D_ + i) = o;
  }
}

// Phase B: in-place prefix combine over the 16 checkpoints (separate kernel --
// merging this loop into k_fused collapses its VGPR alloc to 132 and 2x's it;
// measured twice, r12 + r14).
__global__ void __launch_bounds__(256) k_scanB(const float* __restrict__ lam,
    ushort_t* __restrict__ Wchk){
  const int d = threadIdx.x;
  const int b0 = blockIdx.x * 16;
  float l2 = lam[d]; l2 = l2*l2;
  float l8 = l2*l2;  l8 = l8*l8;        // lam^8
  float W[16];
  #pragma unroll
  for (int r = 0; r < 16; ++r)
    W[r] = bf2f(Wchk[(size_t)(b0+r)*D_ + d]);
  #pragma unroll 1
  for (int j = 0; j < 15; ++j){
    ushort_t* slot = Wchk + (size_t)(j+1)*B_*D_;
    #pragma unroll
    for (int r = 0; r < 16; ++r){
      const float c = bf2f(slot[(size_t)(b0+r)*D_ + d]);
      W[r] = l8*W[r] + c;
      slot[(size_t)(b0+r)*D_ + d] = f2bf(W[r]);
    }
  }
}

// ---------------- fused replay + output GEMM (r13 body + XCD-pair swizzle) ----------------
// Single change vs r13: h moved from bit 0 to bit 3 of blockIdx. The dispatcher
// round-robins consecutive blocks across the 8 XCDs, so bit-0 pairing never
// co-located the h0/h1 pair (identical U+Wchk reads). Pair members 8 apart ->
// same XCD slot -> genuine L2 sharing.
__global__ void __launch_bounds__(256) k_fused(
    const float* __restrict__ U, const ushort_t* __restrict__ Af,
    const ushort_t* __restrict__ Lws, const float* __restrict__ lam,
    const float* __restrict__ dVd, const ushort_t* __restrict__ Wchk,
    float* __restrict__ outZ, float* __restrict__ outY){
  __shared__ __align__(16) ushort_t AfZhL[8*8*512];   // 65536 B
  __shared__ __align__(16) ushort_t LwsL[32*512];     // 32768 B
  __shared__ __align__(16) ushort_t AfYhL[40*512];    // 40960 B
  __shared__ __align__(16) float    trbZ[4][16][68];  // 17408 B
  __shared__ __align__(16) float    dVdL[128];        // 512 B
  __shared__ __align__(16) float    lamL[256];        // 1024 B

  const int tid = threadIdx.x;
  const int d = blockIdx.x;
  const int h  = (d >> 3) & 1;                 // bit 3: pair members 8 apart
  const int pc = (d >> 4)*8 + (d & 7);         // 0..511 (bijective)
  const int ch = pc & 15;
  const int bq = pc >> 4;
  const int wid = tid >> 6, l = tid & 63;
  const int lm = l & 15, lh = l >> 4;
  const int col0 = bq*64 + wid*16;
  const int col = col0 + lm;

  // one-time staging
  {
    const uint4* gsrc = (const uint4*)Af;
    uint4* dz = (uint4*)AfZhL;
    #pragma unroll
    for (int r = 0; r < 16; ++r){
      const int i = r*256 + tid;
      const int f = i >> 6, l4 = i & 63;
      const int mi8 = f >> 3, kc = f & 7;
      dz[i] = gsrc[(size_t)((h*8 + mi8)*10 + kc)*64 + l4];
    }
    uint4* dy = (uint4*)AfYhL;
    const int nY = h ? 640 : 2560;
    const int sb = 16 + (h ? 4 : 0);
    #pragma unroll
    for (int r = 0; r < 10; ++r){
      const int i = r*256 + tid;
      if (i < nY){
        const int f = i >> 6, l4 = i & 63;
        const int myl = f / 10, j = f % 10;
        dy[i] = gsrc[(size_t)((sb + myl)*10 + j)*64 + l4];
      }
    }
    const uint4* ls = (const uint4*)Lws;
    uint4* ld = (uint4*)LwsL;
    #pragma unroll
    for (int r = 0; r < 8; ++r) ld[r*256 + tid] = ls[r*256 + tid];
    if (tid < 32) ((float4*)dVdL)[tid] = ((const float4*)(dVd + h*128))[tid];
    else if (tid < 96) ((float4*)lamL)[tid-32] = ((const float4*)lam)[tid-32];
  }

  // boundary w (slot ch; scanB already combined)
  float w[64];
  #pragma unroll
  for (int kc = 0; kc < 8; ++kc)
    #pragma unroll
    for (int hh = 0; hh < 2; ++hh){
      const int i = 32*kc + 16*hh + 4*lh;
      const ushort4 wu = *(const ushort4*)(Wchk + ((size_t)ch*B_ + col)*D_ + i);
      const int e = 8*kc + 4*hh;
      w[e+0]=bf2f(wu.x); w[e+1]=bf2f(wu.y); w[e+2]=bf2f(wu.z); w[e+3]=bf2f(wu.w);
    }

  // u prefetch
  const size_t TS = (size_t)B_ * UD_;
  const float* Ucol = U + (size_t)col * UD_;
  float4 ua, ub, uc;
  {
    const float* Ut = Ucol + (size_t)(ch*8)*TS;
    ua = *(const float4*)&Ut[4*lh]; ub = *(const float4*)&Ut[16+4*lh]; uc = *(const float4*)&Ut[32+4*lh];
  }

  __syncthreads();   // the only block-wide barrier

#define ZLOOP(HH)                                                               \
  { float* zbase = outZ + ((size_t)t*B_ + col0)*D_ + (HH)*128;                  \
    _Pragma("unroll")                                                           \
    for (int g = 0; g < 2; ++g){                                                \
      _Pragma("unroll")                                                         \
      for (int mi = 0; mi < 4; ++mi){                                           \
        const int mi8 = g*4 + mi;                                               \
        f32x4 acc = {0.f,0.f,0.f,0.f};                                          \
        _Pragma("unroll")                                                       \
        for (int kc = 0; kc < 8; ++kc){                                         \
          const bf16x8 af = *(const bf16x8*)&AfZhL[((mi8*8+kc)*64 + l)*8];      \
          acc = mfma16(af, wfr[kc], acc);                                       \
        }                                                                       \
        const float4 dv = *(const float4*)&dVdL[mi8*16 + 4*lh];                 \
        acc[0] += dv.x * (float)wfr[((HH)*8+mi8)>>1][0 + 4*(mi8&1)];            \
        acc[1] += dv.y * (float)wfr[((HH)*8+mi8)>>1][1 + 4*(mi8&1)];            \
        acc[2] += dv.z * (float)wfr[((HH)*8+mi8)>>1][2 + 4*(mi8&1)];            \
        acc[3] += dv.w * (float)wfr[((HH)*8+mi8)>>1][3 + 4*(mi8&1)];            \
        *(float4*)&trbZ[wid][lm][mi*16 + 4*lh] = make_float4(acc[0],acc[1],acc[2],acc[3]); \
      }                                                                         \
      __builtin_amdgcn_wave_barrier();                                          \
      _Pragma("unroll")                                                         \
      for (int j = 0; j < 4; ++j){                                              \
        const int r_ = j*4 + (l >> 4), c16 = l & 15;                            \
        const float4 v = *(const float4*)&trbZ[wid][r_][4*c16];                 \
        *(float4*)&zbase[(size_t)r_*D_ + g*64 + 4*c16] = v;                     \
      }                                                                         \
      __builtin_amdgcn_wave_barrier();                                          \
    } }

#define YLOOP(COFF, NMY)                                                        \
  { float* yrow = outY + ((size_t)t*B_ + col)*NO_ + (COFF);                     \
    _Pragma("unroll")                                                           \
    for (int my = 0; my < (NMY); ++my){                                         \
      f32x4 acc = {0.f,0.f,0.f,0.f};                                            \
      _Pragma("unroll")                                                         \
      for (int kc = 0; kc < 8; ++kc){                                           \
        const bf16x8 af = *(const bf16x8*)&AfYhL[((my*10+kc)*64 + l)*8];        \
        acc = mfma16(af, wfr[kc], acc);                                         \
      }                                                                         \
      { const bf16x8 af8 = *(const bf16x8*)&AfYhL[((my*10+8)*64 + l)*8];        \
        const bf16x8 af9 = *(const bf16x8*)&AfYhL[((my*10+9)*64 + l)*8];        \
        acc = mfma16(af8, uf0, acc); acc = mfma16(af9, uf1, acc); }             \
      *(float4*)&yrow[my*16 + 4*lh] = make_float4(acc[0],acc[1],acc[2],acc[3]); \
    } }

  #pragma unroll 1
  for (int s = 0; s < 8; ++s){
    const int t = ch*8 + s;
    bf16x8 uf0, uf1;
    {
      union { ushort_t us[8]; bf16x8 v; } cv;
      cv.us[0]=f2bf(ua.x); cv.us[1]=f2bf(ua.y); cv.us[2]=f2bf(ua.z); cv.us[3]=f2bf(ua.w);
      cv.us[4]=f2bf(ub.x); cv.us[5]=f2bf(ub.y); cv.us[6]=f2bf(ub.z); cv.us[7]=f2bf(ub.w);
      uf0 = cv.v;
      cv.us[0]=f2bf(uc.x); cv.us[1]=f2bf(uc.y); cv.us[2]=f2bf(uc.z); cv.us[3]=f2bf(uc.w);
      cv.us[4]=0; cv.us[5]=0; cv.us[6]=0; cv.us[7]=0;
      uf1 = cv.v;
    }
    if (s < 7){
      const float* Ut = Ucol + (size_t)(t+1)*TS;
      ua = *(const float4*)&Ut[4*lh]; ub = *(const float4*)&Ut[16+4*lh]; uc = *(const float4*)&Ut[32+4*lh];
    }
    #pragma unroll
    for (int it = 0; it < 16; ++it){
      const bf16x8 a0 = *(const bf16x8*)&LwsL[((it*2+0)*64 + l)*8];
      const bf16x8 a1 = *(const bf16x8*)&LwsL[((it*2+1)*64 + l)*8];
      const float4 lv = *(const float4*)&lamL[32*(it>>1) + 16*(it&1) + 4*lh];
      f32x4 acc = {0.f,0.f,0.f,0.f};
      acc = mfma16(a0, uf0, acc);
      acc = mfma16(a1, uf1, acc);
      const int e0 = 8*(it>>1) + 4*(it&1);
      w[e0+0] = lv.x*w[e0+0] + acc[0];
      w[e0+1] = lv.y*w[e0+1] + acc[1];
      w[e0+2] = lv.z*w[e0+2] + acc[2];
      w[e0+3] = lv.w*w[e0+3] + acc[3];
    }
    bf16x8 wfr[8];
    #pragma unroll
    for (int kc = 0; kc < 8; ++kc){
      union { ushort_t us[8]; bf16x8 v; } cv;
      #pragma unroll
      for (int j = 0; j < 8; ++j) cv.us[j] = f2bf(w[8*kc + j]);
      wfr[kc] = cv.v;
    }
    if (h == 0){
      ZLOOP(0);
      YLOOP(0, 4);
    } else {
      ZLOOP(1);
      YLOOP(64, 1);
    }
  }
#undef ZLOOP
#undef YLOOP
}

// ---------------- launcher: 7 launches ----------------
extern "C" void kernel_launch(void* const* d_in, const int* in_sizes, int n_in,
                              void* d_out, int out_size, void* d_ws, size_t ws_size,
                              hipStream_t stream){
  const float* z0  = (const float*)d_in[0];
  const float* dt  = (const float*)d_in[2];
  const float* U   = (const float*)d_in[3];
  const float* eig = (const float*)d_in[4];
  const float* V   = (const float*)d_in[5];
  const float* L   = (const float*)d_in[6];
  const float* C   = (const float*)d_in[7];
  const float* Dm  = (const float*)d_in[8];
  float* outZ = (float*)d_out;
  float* outY = outZ + (size_t)T_*B_*D_;

  char* ws = (char*)d_ws;
  float* Wm    = (float*)(ws + 0);        // W = V^2
  float* V3m   = (float*)(ws + 262144);   // V^3
  float* VinvT = (float*)(ws + 524288);   // k3 output
  float* Lw    = (float*)(ws + 786432);
  float* Cw    = (float*)(ws + 835584);
  float* lam   = (float*)(ws + 917504);
  float* dVd   = (float*)(ws + 918528);
  ushort_t* Af   = (ushort_t*)(ws + 919552);
  ushort_t* Lws  = (ushort_t*)(ws + 1134592);
  ushort_t* Wchk = (ushort_t*)(ws + 1167360);
  // V4 parks in Wchk slot-1 space: dead after k3; scanA overwrites later (stream-ordered).
  float* V4m   = (float*)(ws + 1167360 + (size_t)B_*D_*2);
  if (ws_size < 17944576u) return;

  k1     <<<337,256,0,stream>>>(V, eig, C, Wm, Cw, lam, dVd);
  k2     <<<512,256,0,stream>>>(V, Wm, V3m, V4m);
  k3     <<<256,256,0,stream>>>(V, Wm, V3m, V4m, L, dt, VinvT, Lw);
  k_prep2<<<342,256,0,stream>>>(z0, VinvT, Lw, V, Cw, Dm, dt, Wchk, Lws, Af);
  k_scanA<<<1920,256,0,stream>>>(U, Lws, lam, Wchk);
  k_scanB<<<128,256,0,stream>>>(lam, Wchk);
  k_fused<<<1024,256,0,stream>>>(U, Af, Lws, lam, dVd, Wchk, outZ, outY);
}

// Round 16
// 246.296 us; speedup vs baseline: 1.5941x; 1.0704x over previous
//
#include <hip/hip_runtime.h>

#define D_   256
#define UD_  48
#define NO_  80
#define T_   128
#define B_   2048

typedef __bf16 bf16x8 __attribute__((ext_vector_type(8)));
typedef float  f32x4  __attribute__((ext_vector_type(4)));
typedef unsigned short ushort_t;

static __device__ __forceinline__ ushort_t f2bf(float f){
  return __builtin_bit_cast(ushort_t, (__bf16)f);
}
static __device__ __forceinline__ float bf2f(ushort_t u){
  union { unsigned int i; float f; } c; c.i = ((unsigned int)u) << 16; return c.f;
}
static __device__ __forceinline__ f32x4 mfma16(bf16x8 a, bf16x8 b, f32x4 c){
  return __builtin_amdgcn_mfma_f32_16x16x32_bf16(a, b, c, 0, 0, 0);
}

// ---------------- prep: closed-form 2-NS polynomial (verified exact) ----------
// Vinv ~= q(V), q(v)=8-28v+56v^2-70v^3+56v^4-28v^5+8v^6-v^7; 1-v q(v) = (1-v)^8.

// W = V@V (blocks 0..255) | Cw = C@V (256..335) | lam,dVd (336)
__global__ void __launch_bounds__(256) k1(
    const float* __restrict__ V, const float* __restrict__ eig,
    const float* __restrict__ Cmat,
    float* __restrict__ W, float* __restrict__ Cw,
    float* __restrict__ lam, float* __restrict__ dVd){
  const int bid = blockIdx.x, tid = threadIdx.x;
  if (bid < 256){
    const float* Ar = V + bid*D_;
    float a0=0.f,a1=0.f,a2=0.f,a3=0.f;
    #pragma unroll 4
    for (int k = 0; k < D_; k += 4){
      a0 += Ar[k+0] * V[(k+0)*D_ + tid];
      a1 += Ar[k+1] * V[(k+1)*D_ + tid];
      a2 += Ar[k+2] * V[(k+2)*D_ + tid];
      a3 += Ar[k+3] * V[(k+3)*D_ + tid];
    }
    W[bid*D_ + tid] = (a0+a1)+(a2+a3);
  } else if (bid < 256 + NO_){
    const int n = bid - 256;
    float acc = 0.f;
    #pragma unroll 4
    for (int j = 0; j < D_; ++j) acc += Cmat[n*D_ + j] * V[j*D_ + tid];
    Cw[n*D_ + tid] = acc;
  } else {
    lam[tid] = 0.99f / (1.0f + expf(-eig[tid]));
    const float v = V[tid*D_ + tid];
    dVd[tid] = v - bf2f(f2bf(v));
  }
}

// V3 = V@W (blocks 0..255) | V4 = W@W (blocks 256..511)
__global__ void __launch_bounds__(256) k2(
    const float* __restrict__ V, const float* __restrict__ W,
    float* __restrict__ V3, float* __restrict__ V4){
  const int bid = blockIdx.x, tid = threadIdx.x;
  const int i = bid & 255;
  const float* Ar = (bid < 256 ? V : W) + i*D_;
  float a0=0.f,a1=0.f,a2=0.f,a3=0.f;
  #pragma unroll 4
  for (int k = 0; k < D_; k += 4){
    a0 += Ar[k+0] * W[(k+0)*D_ + tid];
    a1 += Ar[k+1] * W[(k+1)*D_ + tid];
    a2 += Ar[k+2] * W[(k+2)*D_ + tid];
    a3 += Ar[k+3] * W[(k+3)*D_ + tid];
  }
  float* dst = (bid < 256) ? V3 : V4;
  dst[i*D_ + tid] = (a0+a1)+(a2+a3);
}

// X2 = [8I -28V +56W -70V3 +56V4] + V4 @ (-28V +8W -V3); writes VinvT + Lw.
__global__ void __launch_bounds__(256) k3(
    const float* __restrict__ V, const float* __restrict__ W,
    const float* __restrict__ V3, const float* __restrict__ V4,
    const float* __restrict__ Lmat, const float* __restrict__ dt,
    float* __restrict__ VinvT, float* __restrict__ Lw){
  __shared__ float row[256];
  const int i = blockIdx.x, j = threadIdx.x;
  const float* r4 = V4 + i*D_;
  float a0=0.f,a1=0.f,a2=0.f,a3=0.f;
  #pragma unroll 4
  for (int k = 0; k < D_; k += 4){
    a0 += r4[k+0] * (-28.f*V[(k+0)*D_+j] + 8.f*W[(k+0)*D_+j] - V3[(k+0)*D_+j]);
    a1 += r4[k+1] * (-28.f*V[(k+1)*D_+j] + 8.f*W[(k+1)*D_+j] - V3[(k+1)*D_+j]);
    a2 += r4[k+2] * (-28.f*V[(k+2)*D_+j] + 8.f*W[(k+2)*D_+j] - V3[(k+2)*D_+j]);
    a3 += r4[k+3] * (-28.f*V[(k+3)*D_+j] + 8.f*W[(k+3)*D_+j] - V3[(k+3)*D_+j]);
  }
  const float out = (i == j ? 8.f : 0.f)
                  - 28.f*V[i*D_+j] + 56.f*W[i*D_+j] - 70.f*V3[i*D_+j] + 56.f*V4[i*D_+j]
                  + ((a0+a1)+(a2+a3));
  VinvT[j*D_ + i] = out;
  row[j] = out;
  __syncthreads();
  if (j < UD_){
    float acc = 0.f;
    #pragma unroll 4
    for (int k = 0; k < D_; ++k) acc += row[k] * Lmat[k*UD_ + j];
    Lw[i*UD_ + j] = acc * dt[0];
  }
}

// w0 = z0@VinvT (blocks 0..255) | Lws pack (256..287) | packA (288..341)
__global__ void __launch_bounds__(256) k_prep2(
    const float* __restrict__ z0, const float* __restrict__ VinvT,
    const float* __restrict__ Lw, const float* __restrict__ V,
    const float* __restrict__ Cw, const float* __restrict__ Dmat,
    const float* __restrict__ dt,
    ushort_t* __restrict__ Wchk, ushort_t* __restrict__ Lws,
    ushort_t* __restrict__ Af){
  __shared__ float zr[8][256];
  const int bid = blockIdx.x, tid = threadIdx.x;
  if (bid < 256){
    const int b0 = bid * 8;
    #pragma unroll
    for (int r = 0; r < 8; ++r) zr[r][tid] = z0[(size_t)(b0+r)*D_ + tid];
    __syncthreads();
    float acc[8] = {0.f,0.f,0.f,0.f,0.f,0.f,0.f,0.f};
    #pragma unroll 4
    for (int j = 0; j < D_; ++j){
      const float vj = VinvT[j*D_ + tid];
      #pragma unroll
      for (int r = 0; r < 8; ++r) acc[r] += zr[r][j] * vj;
    }
    #pragma unroll
    for (int r = 0; r < 8; ++r)
      Wchk[(size_t)(b0+r)*D_ + tid] = f2bf(acc[r]);
  } else if (bid < 288){
    const int f = bid - 256;
    if (tid < 64){
      const int l = tid, lm = l & 15, lh = l >> 4;
      const int it = f >> 1, kc2 = f & 1;
      const int ig = it*16 + lm;
      #pragma unroll
      for (int j = 0; j < 8; ++j){
        const int k = 32*kc2 + 4*lh + (j & 3) + 16*(j >> 2);
        Lws[(f*64 + l)*8 + j] = f2bf(k < UD_ ? Lw[ig*UD_ + k] : 0.f);
      }
    }
  } else {
    const int v = (bid - 288)*4 + (tid >> 6);
    if (v < 210){
      const int mt = v / 10, kc = v % 10;
      const int l = tid & 63, lm = l & 15, lh = l >> 4;
      const float dts = dt[0];
      #pragma unroll
      for (int j = 0; j < 8; ++j){
        const int k = 32*kc + 4*lh + (j & 3) + 16*(j >> 2);
        float val = 0.f;
        if (mt < 16){
          if (kc < 8) val = V[(mt*16 + lm)*D_ + k];
        } else {
          const int n = (mt - 16)*16 + lm;
          if (kc < 8) val = Cw[n*D_ + k];
          else { const int ku = k - 256; if (ku < UD_) val = dts * Dmat[n*UD_ + ku]; }
        }
        Af[((size_t)(mt*10 + kc)*64 + l)*8 + j] = f2bf(val);
      }
    }
  }
}

// ---------------- parallel local-chunk scan (phase A) ----------------
#define LSCAN_STEP(UA, UB, UC) do {                                             \
  union { ushort_t us[8]; bf16x8 v; } c0, c1;                                   \
  c0.us[0]=f2bf((UA).x); c0.us[1]=f2bf((UA).y); c0.us[2]=f2bf((UA).z); c0.us[3]=f2bf((UA).w); \
  c0.us[4]=f2bf((UB).x); c0.us[5]=f2bf((UB).y); c0.us[6]=f2bf((UB).z); c0.us[7]=f2bf((UB).w); \
  c1.us[0]=f2bf((UC).x); c1.us[1]=f2bf((UC).y); c1.us[2]=f2bf((UC).z); c1.us[3]=f2bf((UC).w); \
  c1.us[4]=0; c1.us[5]=0; c1.us[6]=0; c1.us[7]=0;                               \
  _Pragma("unroll")                                                             \
  for (int q = 0; q < 4; ++q){                                                  \
    f32x4 acc = {0.f,0.f,0.f,0.f};                                              \
    acc = mfma16(lwf[q*2+0], c0.v, acc);                                        \
    acc = mfma16(lwf[q*2+1], c1.v, acc);                                        \
    _Pragma("unroll")                                                           \
    for (int r = 0; r < 4; ++r) w[q*4+r] = lamr[q*4+r]*w[q*4+r] + acc[r];       \
  }                                                                             \
} while(0)

// 1920 blocks = 15 ch x 128 bq; chunk ch's local 8-step scan from zero state;
// writes c_ch into Wchk slot ch+1 (bf16).
__global__ void __launch_bounds__(256) k_scanA(const float* __restrict__ U,
    const ushort_t* __restrict__ Lws, const float* __restrict__ lam,
    ushort_t* __restrict__ Wchk){
  const int tid = threadIdx.x;
  const int wid = tid >> 6, l = tid & 63;
  const int lm = l & 15, lh = l >> 4;
  const int ch = blockIdx.x >> 7;        // 0..14
  const int bq = blockIdx.x & 127;
  const int row = bq*16 + lm;
  const int itb = wid*4;

  bf16x8 lwf[8];
  #pragma unroll
  for (int q = 0; q < 4; ++q)
    #pragma unroll
    for (int c = 0; c < 2; ++c)
      lwf[q*2 + c] = *(const bf16x8*)(Lws + ((size_t)(((itb+q)*2 + c)*64 + l))*8);

  float lamr[16], w[16];
  #pragma unroll
  for (int q = 0; q < 4; ++q){
    const int i = (itb+q)*16 + 4*lh;
    const float4 lv = *(const float4*)&lam[i];
    lamr[q*4+0]=lv.x; lamr[q*4+1]=lv.y; lamr[q*4+2]=lv.z; lamr[q*4+3]=lv.w;
    w[q*4+0]=0.f; w[q*4+1]=0.f; w[q*4+2]=0.f; w[q*4+3]=0.f;
  }

  const size_t TS = (size_t)B_ * UD_;
  const float* Urow = U + ((size_t)(ch*8)*B_ + row) * UD_;
  float4 Aa, Ab, Ac, Ba, Bb, Bc;
  Aa = *(const float4*)&Urow[4*lh]; Ab = *(const float4*)&Urow[16+4*lh]; Ac = *(const float4*)&Urow[32+4*lh];
  { const float* Up = Urow + TS;
    Ba = *(const float4*)&Up[4*lh]; Bb = *(const float4*)&Up[16+4*lh]; Bc = *(const float4*)&Up[32+4*lh]; }

  #pragma unroll
  for (int tt = 0; tt < 4; ++tt){
    LSCAN_STEP(Aa, Ab, Ac);
    if (tt < 3){
      const float* Up = Urow + (size_t)(2*tt+2)*TS;
      Aa = *(const float4*)&Up[4*lh]; Ab = *(const float4*)&Up[16+4*lh]; Ac = *(const float4*)&Up[32+4*lh];
    }
    LSCAN_STEP(Ba, Bb, Bc);
    if (tt < 3){
      const float* Up = Urow + (size_t)(2*tt+3)*TS;
      Ba = *(const float4*)&Up[4*lh]; Bb = *(const float4*)&Up[16+4*lh]; Bc = *(const float4*)&Up[32+4*lh];
    }
  }
  #pragma unroll
  for (int q = 0; q < 4; ++q){
    const int i = (itb+q)*16 + 4*lh;
    ushort4 o; o.x=f2bf(w[q*4+0]); o.y=f2bf(w[q*4+1]); o.z=f2bf(w[q*4+2]); o.w=f2bf(w[q*4+3]);
    *(ushort4*)(Wchk + ((size_t)(ch+1)*B_ + row)*D_ + i) = o;
  }
}

// Phase B: in-place prefix combine over the 16 checkpoints (separate kernel --
// merging this loop into k_fused collapses its VGPR alloc to 132 and 2x's it;
// measured twice, r12 + r14).
__global__ void __launch_bounds__(256) k_scanB(const float* __restrict__ lam,
    ushort_t* __restrict__ Wchk){
  const int d = threadIdx.x;
  const int b0 = blockIdx.x * 16;
  float l2 = lam[d]; l2 = l2*l2;
  float l8 = l2*l2;  l8 = l8*l8;        // lam^8
  float W[16];
  #pragma unroll
  for (int r = 0; r < 16; ++r)
    W[r] = bf2f(Wchk[(size_t)(b0+r)*D_ + d]);
  #pragma unroll 1
  for (int j = 0; j < 15; ++j){
    ushort_t* slot = Wchk + (size_t)(j+1)*B_*D_;
    #pragma unroll
    for (int r = 0; r < 16; ++r){
      const float c = bf2f(slot[(size_t)(b0+r)*D_ + d]);
      W[r] = l8*W[r] + c;
      slot[(size_t)(b0+r)*D_ + d] = f2bf(W[r]);
    }
  }
}

// ---------------- fused replay + output GEMM (r13 body; 2 ch per block) ----------------
// Single change vs r13: 512 blocks, each serving TWO consecutive ch values with one
// LDS staging pass (cc loop is compile-time trip-2, fully unrolled -- runtime-bounded
// pre-loops are the twice-measured VGPR-collapse trigger, r12/r14). Halves staging
// traffic and per-tranche drain bubbles (4 tranches/CU -> 2).
// r15's bit-3 XCD swizzle measured +8us -> reverted to r13's bit-0 h layout.
__global__ void __launch_bounds__(256) k_fused(
    const float* __restrict__ U, const ushort_t* __restrict__ Af,
    const ushort_t* __restrict__ Lws, const float* __restrict__ lam,
    const float* __restrict__ dVd, const ushort_t* __restrict__ Wchk,
    float* __restrict__ outZ, float* __restrict__ outY){
  __shared__ __align__(16) ushort_t AfZhL[8*8*512];   // 65536 B
  __shared__ __align__(16) ushort_t LwsL[32*512];     // 32768 B
  __shared__ __align__(16) ushort_t AfYhL[40*512];    // 40960 B
  __shared__ __align__(16) float    trbZ[4][16][68];  // 17408 B
  __shared__ __align__(16) float    dVdL[128];        // 512 B
  __shared__ __align__(16) float    lamL[256];        // 1024 B

  const int tid = threadIdx.x;
  const int bid = blockIdx.x;
  const int h   = bid & 1;
  const int chp = (bid >> 1) & 7;       // ch pair: serves chp*2 and chp*2+1
  const int bq  = bid >> 4;
  const int wid = tid >> 6, l = tid & 63;
  const int lm = l & 15, lh = l >> 4;
  const int col0 = bq*64 + wid*16;
  const int col = col0 + lm;

  // one-time staging
  {
    const uint4* gsrc = (const uint4*)Af;
    uint4* dz = (uint4*)AfZhL;
    #pragma unroll
    for (int r = 0; r < 16; ++r){
      const int i = r*256 + tid;
      const int f = i >> 6, l4 = i & 63;
      const int mi8 = f >> 3, kc = f & 7;
      dz[i] = gsrc[(size_t)((h*8 + mi8)*10 + kc)*64 + l4];
    }
    uint4* dy = (uint4*)AfYhL;
    const int nY = h ? 640 : 2560;
    const int sb = 16 + (h ? 4 : 0);
    #pragma unroll
    for (int r = 0; r < 10; ++r){
      const int i = r*256 + tid;
      if (i < nY){
        const int f = i >> 6, l4 = i & 63;
        const int myl = f / 10, j = f % 10;
        dy[i] = gsrc[(size_t)((sb + myl)*10 + j)*64 + l4];
      }
    }
    const uint4* ls = (const uint4*)Lws;
    uint4* ld = (uint4*)LwsL;
    #pragma unroll
    for (int r = 0; r < 8; ++r) ld[r*256 + tid] = ls[r*256 + tid];
    if (tid < 32) ((float4*)dVdL)[tid] = ((const float4*)(dVd + h*128))[tid];
    else if (tid < 96) ((float4*)lamL)[tid-32] = ((const float4*)lam)[tid-32];
  }

  __syncthreads();   // the only block-wide barrier

  const size_t TS = (size_t)B_ * UD_;
  const float* Ucol = U + (size_t)col * UD_;

#define ZLOOP(HH)                                                               \
  { float* zbase = outZ + ((size_t)t*B_ + col0)*D_ + (HH)*128;                  \
    _Pragma("unroll")                                                           \
    for (int g = 0; g < 2; ++g){                                                \
      _Pragma("unroll")                                                         \
      for (int mi = 0; mi < 4; ++mi){                                           \
        const int mi8 = g*4 + mi;                                               \
        f32x4 acc = {0.f,0.f,0.f,0.f};                                          \
        _Pragma("unroll")                                                       \
        for (int kc = 0; kc < 8; ++kc){                                         \
          const bf16x8 af = *(const bf16x8*)&AfZhL[((mi8*8+kc)*64 + l)*8];      \
          acc = mfma16(af, wfr[kc], acc);                                       \
        }                                                                       \
        const float4 dv = *(const float4*)&dVdL[mi8*16 + 4*lh];                 \
        acc[0] += dv.x * (float)wfr[((HH)*8+mi8)>>1][0 + 4*(mi8&1)];            \
        acc[1] += dv.y * (float)wfr[((HH)*8+mi8)>>1][1 + 4*(mi8&1)];            \
        acc[2] += dv.z * (float)wfr[((HH)*8+mi8)>>1][2 + 4*(mi8&1)];            \
        acc[3] += dv.w * (float)wfr[((HH)*8+mi8)>>1][3 + 4*(mi8&1)];            \
        *(float4*)&trbZ[wid][lm][mi*16 + 4*lh] = make_float4(acc[0],acc[1],acc[2],acc[3]); \
      }                                                                         \
      __builtin_amdgcn_wave_barrier();                                          \
      _Pragma("unroll")                                                         \
      for (int j = 0; j < 4; ++j){                                              \
        const int r_ = j*4 + (l >> 4), c16 = l & 15;                            \
        const float4 v = *(const float4*)&trbZ[wid][r_][4*c16];                 \
        *(float4*)&zbase[(size_t)r_*D_ + g*64 + 4*c16] = v;                     \
      }                                                                         \
      __builtin_amdgcn_wave_barrier();                                          \
    } }

#define YLOOP(COFF, NMY)                                                        \
  { float* yrow = outY + ((size_t)t*B_ + col)*NO_ + (COFF);                     \
    _Pragma("unroll")                                                           \
    for (int my = 0; my < (NMY); ++my){                                         \
      f32x4 acc = {0.f,0.f,0.f,0.f};                                            \
      _Pragma("unroll")                                                         \
      for (int kc = 0; kc < 8; ++kc){                                           \
        const bf16x8 af = *(const bf16x8*)&AfYhL[((my*10+kc)*64 + l)*8];        \
        acc = mfma16(af, wfr[kc], acc);                                         \
      }                                                                         \
      { const bf16x8 af8 = *(const bf16x8*)&AfYhL[((my*10+8)*64 + l)*8];        \
        const bf16x8 af9 = *(const bf16x8*)&AfYhL[((my*10+9)*64 + l)*8];        \
        acc = mfma16(af8, uf0, acc); acc = mfma16(af9, uf1, acc); }             \
      *(float4*)&yrow[my*16 + 4*lh] = make_float4(acc[0],acc[1],acc[2],acc[3]); \
    } }

  #pragma unroll
  for (int cc = 0; cc < 2; ++cc){
    const int ch = chp*2 + cc;

    // boundary w (slot ch; scanB already combined)
    float w[64];
    #pragma unroll
    for (int kc = 0; kc < 8; ++kc)
      #pragma unroll
      for (int hh = 0; hh < 2; ++hh){
        const int i = 32*kc + 16*hh + 4*lh;
        const ushort4 wu = *(const ushort4*)(Wchk + ((size_t)ch*B_ + col)*D_ + i);
        const int e = 8*kc + 4*hh;
        w[e+0]=bf2f(wu.x); w[e+1]=bf2f(wu.y); w[e+2]=bf2f(wu.z); w[e+3]=bf2f(wu.w);
      }

    // u prefetch for this ch's first step
    float4 ua, ub, uc;
    {
      const float* Ut = Ucol + (size_t)(ch*8)*TS;
      ua = *(const float4*)&Ut[4*lh]; ub = *(const float4*)&Ut[16+4*lh]; uc = *(const float4*)&Ut[32+4*lh];
    }

    #pragma unroll 1
    for (int s = 0; s < 8; ++s){
      const int t = ch*8 + s;
      bf16x8 uf0, uf1;
      {
        union { ushort_t us[8]; bf16x8 v; } cv;
        cv.us[0]=f2bf(ua.x); cv.us[1]=f2bf(ua.y); cv.us[2]=f2bf(ua.z); cv.us[3]=f2bf(ua.w);
        cv.us[4]=f2bf(ub.x); cv.us[5]=f2bf(ub.y); cv.us[6]=f2bf(ub.z); cv.us[7]=f2bf(ub.w);
        uf0 = cv.v;
        cv.us[0]=f2bf(uc.x); cv.us[1]=f2bf(uc.y); cv.us[2]=f2bf(uc.z); cv.us[3]=f2bf(uc.w);
        cv.us[4]=0; cv.us[5]=0; cv.us[6]=0; cv.us[7]=0;
        uf1 = cv.v;
      }
      if (s < 7){
        const float* Ut = Ucol + (size_t)(t+1)*TS;
        ua = *(const float4*)&Ut[4*lh]; ub = *(const float4*)&Ut[16+4*lh]; uc = *(const float4*)&Ut[32+4*lh];
      }
      #pragma unroll
      for (int it = 0; it < 16; ++it){
        const bf16x8 a0 = *(const bf16x8*)&LwsL[((it*2+0)*64 + l)*8];
        const bf16x8 a1 = *(const bf16x8*)&LwsL[((it*2+1)*64 + l)*8];
        const float4 lv = *(const float4*)&lamL[32*(it>>1) + 16*(it&1) + 4*lh];
        f32x4 acc = {0.f,0.f,0.f,0.f};
        acc = mfma16(a0, uf0, acc);
        acc = mfma16(a1, uf1, acc);
        const int e0 = 8*(it>>1) + 4*(it&1);
        w[e0+0] = lv.x*w[e0+0] + acc[0];
        w[e0+1] = lv.y*w[e0+1] + acc[1];
        w[e0+2] = lv.z*w[e0+2] + acc[2];
        w[e0+3] = lv.w*w[e0+3] + acc[3];
      }
      bf16x8 wfr[8];
      #pragma unroll
      for (int kc = 0; kc < 8; ++kc){
        union { ushort_t us[8]; bf16x8 v; } cv;
        #pragma unroll
        for (int j = 0; j < 8; ++j) cv.us[j] = f2bf(w[8*kc + j]);
        wfr[kc] = cv.v;
      }
      if (h == 0){
        ZLOOP(0);
        YLOOP(0, 4);
      } else {
        ZLOOP(1);
        YLOOP(64, 1);
      }
    }
  }
#undef ZLOOP
#undef YLOOP
}

// ---------------- launcher: 7 launches ----------------
extern "C" void kernel_launch(void* const* d_in, const int* in_sizes, int n_in,
                              void* d_out, int out_size, void* d_ws, size_t ws_size,
                              hipStream_t stream){
  const float* z0  = (const float*)d_in[0];
  const float* dt  = (const float*)d_in[2];
  const float* U   = (const float*)d_in[3];
  const float* eig = (const float*)d_in[4];
  const float* V   = (const float*)d_in[5];
  const float* L   = (const float*)d_in[6];
  const float* C   = (const float*)d_in[7];
  const float* Dm  = (const float*)d_in[8];
  float* outZ = (float*)d_out;
  float* outY = outZ + (size_t)T_*B_*D_;

  char* ws = (char*)d_ws;
  float* Wm    = (float*)(ws + 0);        // W = V^2
  float* V3m   = (float*)(ws + 262144);   // V^3
  float* VinvT = (float*)(ws + 524288);   // k3 output
  float* Lw    = (float*)(ws + 786432);
  float* Cw    = (float*)(ws + 835584);
  float* lam   = (float*)(ws + 917504);
  float* dVd   = (float*)(ws + 918528);
  ushort_t* Af   = (ushort_t*)(ws + 919552);
  ushort_t* Lws  = (ushort_t*)(ws + 1134592);
  ushort_t* Wchk = (ushort_t*)(ws + 1167360);
  // V4 parks in Wchk slot-1 space: dead after k3; scanA overwrites later (stream-ordered).
  float* V4m   = (float*)(ws + 1167360 + (size_t)B_*D_*2);
  if (ws_size < 17944576u) return;

  k1     <<<337,256,0,stream>>>(V, eig, C, Wm, Cw, lam, dVd);
  k2     <<<512,256,0,stream>>>(V, Wm, V3m, V4m);
  k3     <<<256,256,0,stream>>>(V, Wm, V3m, V4m, L, dt, VinvT, Lw);
  k_prep2<<<342,256,0,stream>>>(z0, VinvT, Lw, V, Cw, Dm, dt, Wchk, Lws, Af);
  k_scanA<<<1920,256,0,stream>>>(U, Lws, lam, Wchk);
  k_scanB<<<128,256,0,stream>>>(lam, Wchk);
  k_fused<<<512,256,0,stream>>>(U, Af, Lws, lam, dVd, Wchk, outZ, outY);
}

// Round 17
// 234.335 us; speedup vs baseline: 1.6754x; 1.0510x over previous
//
#include <hip/hip_runtime.h>

#define D_   256
#define UD_  48
#define NO_  80
#define T_   128
#define B_   2048

typedef __bf16 bf16x8 __attribute__((ext_vector_type(8)));
typedef float  f32x4  __attribute__((ext_vector_type(4)));
typedef unsigned short ushort_t;

static __device__ __forceinline__ ushort_t f2bf(float f){
  return __builtin_bit_cast(ushort_t, (__bf16)f);
}
static __device__ __forceinline__ float bf2f(ushort_t u){
  union { unsigned int i; float f; } c; c.i = ((unsigned int)u) << 16; return c.f;
}
static __device__ __forceinline__ f32x4 mfma16(bf16x8 a, bf16x8 b, f32x4 c){
  return __builtin_amdgcn_mfma_f32_16x16x32_bf16(a, b, c, 0, 0, 0);
}

// ---------------- prep: closed-form 2-NS polynomial (verified exact) ----------
// Vinv ~= q(V), q(v)=8-28v+56v^2-70v^3+56v^4-28v^5+8v^6-v^7; 1-v q(v) = (1-v)^8.

// W = V@V (blocks 0..255) | Cw = C@V (256..335) | lam,dVd (336)
__global__ void __launch_bounds__(256) k1(
    const float* __restrict__ V, const float* __restrict__ eig,
    const float* __restrict__ Cmat,
    float* __restrict__ W, float* __restrict__ Cw,
    float* __restrict__ lam, float* __restrict__ dVd){
  const int bid = blockIdx.x, tid = threadIdx.x;
  if (bid < 256){
    const float* Ar = V + bid*D_;
    float a0=0.f,a1=0.f,a2=0.f,a3=0.f;
    #pragma unroll 4
    for (int k = 0; k < D_; k += 4){
      a0 += Ar[k+0] * V[(k+0)*D_ + tid];
      a1 += Ar[k+1] * V[(k+1)*D_ + tid];
      a2 += Ar[k+2] * V[(k+2)*D_ + tid];
      a3 += Ar[k+3] * V[(k+3)*D_ + tid];
    }
    W[bid*D_ + tid] = (a0+a1)+(a2+a3);
  } else if (bid < 256 + NO_){
    const int n = bid - 256;
    float acc = 0.f;
    #pragma unroll 4
    for (int j = 0; j < D_; ++j) acc += Cmat[n*D_ + j] * V[j*D_ + tid];
    Cw[n*D_ + tid] = acc;
  } else {
    lam[tid] = 0.99f / (1.0f + expf(-eig[tid]));
    const float v = V[tid*D_ + tid];
    dVd[tid] = v - bf2f(f2bf(v));
  }
}

// V3 = V@W (blocks 0..255) | V4 = W@W (blocks 256..511)
__global__ void __launch_bounds__(256) k2(
    const float* __restrict__ V, const float* __restrict__ W,
    float* __restrict__ V3, float* __restrict__ V4){
  const int bid = blockIdx.x, tid = threadIdx.x;
  const int i = bid & 255;
  const float* Ar = (bid < 256 ? V : W) + i*D_;
  float a0=0.f,a1=0.f,a2=0.f,a3=0.f;
  #pragma unroll 4
  for (int k = 0; k < D_; k += 4){
    a0 += Ar[k+0] * W[(k+0)*D_ + tid];
    a1 += Ar[k+1] * W[(k+1)*D_ + tid];
    a2 += Ar[k+2] * W[(k+2)*D_ + tid];
    a3 += Ar[k+3] * W[(k+3)*D_ + tid];
  }
  float* dst = (bid < 256) ? V3 : V4;
  dst[i*D_ + tid] = (a0+a1)+(a2+a3);
}

// X2 = [8I -28V +56W -70V3 +56V4] + V4 @ (-28V +8W -V3); writes VinvT + Lw.
__global__ void __launch_bounds__(256) k3(
    const float* __restrict__ V, const float* __restrict__ W,
    const float* __restrict__ V3, const float* __restrict__ V4,
    const float* __restrict__ Lmat, const float* __restrict__ dt,
    float* __restrict__ VinvT, float* __restrict__ Lw){
  __shared__ float row[256];
  const int i = blockIdx.x, j = threadIdx.x;
  const float* r4 = V4 + i*D_;
  float a0=0.f,a1=0.f,a2=0.f,a3=0.f;
  #pragma unroll 4
  for (int k = 0; k < D_; k += 4){
    a0 += r4[k+0] * (-28.f*V[(k+0)*D_+j] + 8.f*W[(k+0)*D_+j] - V3[(k+0)*D_+j]);
    a1 += r4[k+1] * (-28.f*V[(k+1)*D_+j] + 8.f*W[(k+1)*D_+j] - V3[(k+1)*D_+j]);
    a2 += r4[k+2] * (-28.f*V[(k+2)*D_+j] + 8.f*W[(k+2)*D_+j] - V3[(k+2)*D_+j]);
    a3 += r4[k+3] * (-28.f*V[(k+3)*D_+j] + 8.f*W[(k+3)*D_+j] - V3[(k+3)*D_+j]);
  }
  const float out = (i == j ? 8.f : 0.f)
                  - 28.f*V[i*D_+j] + 56.f*W[i*D_+j] - 70.f*V3[i*D_+j] + 56.f*V4[i*D_+j]
                  + ((a0+a1)+(a2+a3));
  VinvT[j*D_ + i] = out;
  row[j] = out;
  __syncthreads();
  if (j < UD_){
    float acc = 0.f;
    #pragma unroll 4
    for (int k = 0; k < D_; ++k) acc += row[k] * Lmat[k*UD_ + j];
    Lw[i*UD_ + j] = acc * dt[0];
  }
}

// w0 = z0@VinvT (blocks 0..255) | Lws pack (256..287) | packA (288..341)
__global__ void __launch_bounds__(256) k_prep2(
    const float* __restrict__ z0, const float* __restrict__ VinvT,
    const float* __restrict__ Lw, const float* __restrict__ V,
    const float* __restrict__ Cw, const float* __restrict__ Dmat,
    const float* __restrict__ dt,
    ushort_t* __restrict__ Wchk, ushort_t* __restrict__ Lws,
    ushort_t* __restrict__ Af){
  __shared__ float zr[8][256];
  const int bid = blockIdx.x, tid = threadIdx.x;
  if (bid < 256){
    const int b0 = bid * 8;
    #pragma unroll
    for (int r = 0; r < 8; ++r) zr[r][tid] = z0[(size_t)(b0+r)*D_ + tid];
    __syncthreads();
    float acc[8] = {0.f,0.f,0.f,0.f,0.f,0.f,0.f,0.f};
    #pragma unroll 4
    for (int j = 0; j < D_; ++j){
      const float vj = VinvT[j*D_ + tid];
      #pragma unroll
      for (int r = 0; r < 8; ++r) acc[r] += zr[r][j] * vj;
    }
    #pragma unroll
    for (int r = 0; r < 8; ++r)
      Wchk[(size_t)(b0+r)*D_ + tid] = f2bf(acc[r]);
  } else if (bid < 288){
    const int f = bid - 256;
    if (tid < 64){
      const int l = tid, lm = l & 15, lh = l >> 4;
      const int it = f >> 1, kc2 = f & 1;
      const int ig = it*16 + lm;
      #pragma unroll
      for (int j = 0; j < 8; ++j){
        const int k = 32*kc2 + 4*lh + (j & 3) + 16*(j >> 2);
        Lws[(f*64 + l)*8 + j] = f2bf(k < UD_ ? Lw[ig*UD_ + k] : 0.f);
      }
    }
  } else {
    const int v = (bid - 288)*4 + (tid >> 6);
    if (v < 210){
      const int mt = v / 10, kc = v % 10;
      const int l = tid & 63, lm = l & 15, lh = l >> 4;
      const float dts = dt[0];
      #pragma unroll
      for (int j = 0; j < 8; ++j){
        const int k = 32*kc + 4*lh + (j & 3) + 16*(j >> 2);
        float val = 0.f;
        if (mt < 16){
          if (kc < 8) val = V[(mt*16 + lm)*D_ + k];
        } else {
          const int n = (mt - 16)*16 + lm;
          if (kc < 8) val = Cw[n*D_ + k];
          else { const int ku = k - 256; if (ku < UD_) val = dts * Dmat[n*UD_ + ku]; }
        }
        Af[((size_t)(mt*10 + kc)*64 + l)*8 + j] = f2bf(val);
      }
    }
  }
}

// ---------------- parallel local-chunk scan (phase A) ----------------
#define LSCAN_STEP(UA, UB, UC) do {                                             \
  union { ushort_t us[8]; bf16x8 v; } c0, c1;                                   \
  c0.us[0]=f2bf((UA).x); c0.us[1]=f2bf((UA).y); c0.us[2]=f2bf((UA).z); c0.us[3]=f2bf((UA).w); \
  c0.us[4]=f2bf((UB).x); c0.us[5]=f2bf((UB).y); c0.us[6]=f2bf((UB).z); c0.us[7]=f2bf((UB).w); \
  c1.us[0]=f2bf((UC).x); c1.us[1]=f2bf((UC).y); c1.us[2]=f2bf((UC).z); c1.us[3]=f2bf((UC).w); \
  c1.us[4]=0; c1.us[5]=0; c1.us[6]=0; c1.us[7]=0;                               \
  _Pragma("unroll")                                                             \
  for (int q = 0; q < 4; ++q){                                                  \
    f32x4 acc = {0.f,0.f,0.f,0.f};                                              \
    acc = mfma16(lwf[q*2+0], c0.v, acc);                                        \
    acc = mfma16(lwf[q*2+1], c1.v, acc);                                        \
    _Pragma("unroll")                                                           \
    for (int r = 0; r < 4; ++r) w[q*4+r] = lamr[q*4+r]*w[q*4+r] + acc[r];       \
  }                                                                             \
} while(0)

// 1920 blocks = 15 ch x 128 bq; chunk ch's local 8-step scan from zero state;
// writes c_ch into Wchk slot ch+1 (bf16).
__global__ void __launch_bounds__(256) k_scanA(const float* __restrict__ U,
    const ushort_t* __restrict__ Lws, const float* __restrict__ lam,
    ushort_t* __restrict__ Wchk){
  const int tid = threadIdx.x;
  const int wid = tid >> 6, l = tid & 63;
  const int lm = l & 15, lh = l >> 4;
  const int ch = blockIdx.x >> 7;        // 0..14
  const int bq = blockIdx.x & 127;
  const int row = bq*16 + lm;
  const int itb = wid*4;

  bf16x8 lwf[8];
  #pragma unroll
  for (int q = 0; q < 4; ++q)
    #pragma unroll
    for (int c = 0; c < 2; ++c)
      lwf[q*2 + c] = *(const bf16x8*)(Lws + ((size_t)(((itb+q)*2 + c)*64 + l))*8);

  float lamr[16], w[16];
  #pragma unroll
  for (int q = 0; q < 4; ++q){
    const int i = (itb+q)*16 + 4*lh;
    const float4 lv = *(const float4*)&lam[i];
    lamr[q*4+0]=lv.x; lamr[q*4+1]=lv.y; lamr[q*4+2]=lv.z; lamr[q*4+3]=lv.w;
    w[q*4+0]=0.f; w[q*4+1]=0.f; w[q*4+2]=0.f; w[q*4+3]=0.f;
  }

  const size_t TS = (size_t)B_ * UD_;
  const float* Urow = U + ((size_t)(ch*8)*B_ + row) * UD_;
  float4 Aa, Ab, Ac, Ba, Bb, Bc;
  Aa = *(const float4*)&Urow[4*lh]; Ab = *(const float4*)&Urow[16+4*lh]; Ac = *(const float4*)&Urow[32+4*lh];
  { const float* Up = Urow + TS;
    Ba = *(const float4*)&Up[4*lh]; Bb = *(const float4*)&Up[16+4*lh]; Bc = *(const float4*)&Up[32+4*lh]; }

  #pragma unroll
  for (int tt = 0; tt < 4; ++tt){
    LSCAN_STEP(Aa, Ab, Ac);
    if (tt < 3){
      const float* Up = Urow + (size_t)(2*tt+2)*TS;
      Aa = *(const float4*)&Up[4*lh]; Ab = *(const float4*)&Up[16+4*lh]; Ac = *(const float4*)&Up[32+4*lh];
    }
    LSCAN_STEP(Ba, Bb, Bc);
    if (tt < 3){
      const float* Up = Urow + (size_t)(2*tt+3)*TS;
      Ba = *(const float4*)&Up[4*lh]; Bb = *(const float4*)&Up[16+4*lh]; Bc = *(const float4*)&Up[32+4*lh];
    }
  }
  #pragma unroll
  for (int q = 0; q < 4; ++q){
    const int i = (itb+q)*16 + 4*lh;
    ushort4 o; o.x=f2bf(w[q*4+0]); o.y=f2bf(w[q*4+1]); o.z=f2bf(w[q*4+2]); o.w=f2bf(w[q*4+3]);
    *(ushort4*)(Wchk + ((size_t)(ch+1)*B_ + row)*D_ + i) = o;
  }
}

// Phase B: in-place prefix combine over the 16 checkpoints (separate kernel --
// merging this loop into k_fused collapses its VGPR alloc to 132 and 2x's it;
// measured twice, r12 + r14).
__global__ void __launch_bounds__(256) k_scanB(const float* __restrict__ lam,
    ushort_t* __restrict__ Wchk){
  const int d = threadIdx.x;
  const int b0 = blockIdx.x * 16;
  float l2 = lam[d]; l2 = l2*l2;
  float l8 = l2*l2;  l8 = l8*l8;        // lam^8
  float W[16];
  #pragma unroll
  for (int r = 0; r < 16; ++r)
    W[r] = bf2f(Wchk[(size_t)(b0+r)*D_ + d]);
  #pragma unroll 1
  for (int j = 0; j < 15; ++j){
    ushort_t* slot = Wchk + (size_t)(j+1)*B_*D_;
    #pragma unroll
    for (int r = 0; r < 16; ++r){
      const float c = bf2f(slot[(size_t)(b0+r)*D_ + d]);
      W[r] = l8*W[r] + c;
      slot[(size_t)(b0+r)*D_ + d] = f2bf(W[r]);
    }
  }
}

// ---------------- fused replay + output GEMM (r16 body; 4 ch per block) ----------------
// Single change vs r16: 256 blocks (= exactly 1/CU), each serving FOUR consecutive
// ch values from one LDS staging pass (cc loop compile-time trip-4, fully unrolled
// -- same safe pattern as r16's trip-2; runtime-bounded pre-loops are the VGPR-
// collapse trigger, r12/r14). Tranches/CU: 2 -> 1; staging traffic halves again.
__global__ void __launch_bounds__(256) k_fused(
    const float* __restrict__ U, const ushort_t* __restrict__ Af,
    const ushort_t* __restrict__ Lws, const float* __restrict__ lam,
    const float* __restrict__ dVd, const ushort_t* __restrict__ Wchk,
    float* __restrict__ outZ, float* __restrict__ outY){
  __shared__ __align__(16) ushort_t AfZhL[8*8*512];   // 65536 B
  __shared__ __align__(16) ushort_t LwsL[32*512];     // 32768 B
  __shared__ __align__(16) ushort_t AfYhL[40*512];    // 40960 B
  __shared__ __align__(16) float    trbZ[4][16][68];  // 17408 B
  __shared__ __align__(16) float    dVdL[128];        // 512 B
  __shared__ __align__(16) float    lamL[256];        // 1024 B

  const int tid = threadIdx.x;
  const int bid = blockIdx.x;
  const int h   = bid & 1;
  const int chq = (bid >> 1) & 3;       // ch quad: serves chq*4 .. chq*4+3
  const int bq  = bid >> 3;
  const int wid = tid >> 6, l = tid & 63;
  const int lm = l & 15, lh = l >> 4;
  const int col0 = bq*64 + wid*16;
  const int col = col0 + lm;

  // one-time staging
  {
    const uint4* gsrc = (const uint4*)Af;
    uint4* dz = (uint4*)AfZhL;
    #pragma unroll
    for (int r = 0; r < 16; ++r){
      const int i = r*256 + tid;
      const int f = i >> 6, l4 = i & 63;
      const int mi8 = f >> 3, kc = f & 7;
      dz[i] = gsrc[(size_t)((h*8 + mi8)*10 + kc)*64 + l4];
    }
    uint4* dy = (uint4*)AfYhL;
    const int nY = h ? 640 : 2560;
    const int sb = 16 + (h ? 4 : 0);
    #pragma unroll
    for (int r = 0; r < 10; ++r){
      const int i = r*256 + tid;
      if (i < nY){
        const int f = i >> 6, l4 = i & 63;
        const int myl = f / 10, j = f % 10;
        dy[i] = gsrc[(size_t)((sb + myl)*10 + j)*64 + l4];
      }
    }
    const uint4* ls = (const uint4*)Lws;
    uint4* ld = (uint4*)LwsL;
    #pragma unroll
    for (int r = 0; r < 8; ++r) ld[r*256 + tid] = ls[r*256 + tid];
    if (tid < 32) ((float4*)dVdL)[tid] = ((const float4*)(dVd + h*128))[tid];
    else if (tid < 96) ((float4*)lamL)[tid-32] = ((const float4*)lam)[tid-32];
  }

  __syncthreads();   // the only block-wide barrier

  const size_t TS = (size_t)B_ * UD_;
  const float* Ucol = U + (size_t)col * UD_;

#define ZLOOP(HH)                                                               \
  { float* zbase = outZ + ((size_t)t*B_ + col0)*D_ + (HH)*128;                  \
    _Pragma("unroll")                                                           \
    for (int g = 0; g < 2; ++g){                                                \
      _Pragma("unroll")                                                         \
      for (int mi = 0; mi < 4; ++mi){                                           \
        const int mi8 = g*4 + mi;                                               \
        f32x4 acc = {0.f,0.f,0.f,0.f};                                          \
        _Pragma("unroll")                                                       \
        for (int kc = 0; kc < 8; ++kc){                                         \
          const bf16x8 af = *(const bf16x8*)&AfZhL[((mi8*8+kc)*64 + l)*8];      \
          acc = mfma16(af, wfr[kc], acc);                                       \
        }                                                                       \
        const float4 dv = *(const float4*)&dVdL[mi8*16 + 4*lh];                 \
        acc[0] += dv.x * (float)wfr[((HH)*8+mi8)>>1][0 + 4*(mi8&1)];            \
        acc[1] += dv.y * (float)wfr[((HH)*8+mi8)>>1][1 + 4*(mi8&1)];            \
        acc[2] += dv.z * (float)wfr[((HH)*8+mi8)>>1][2 + 4*(mi8&1)];            \
        acc[3] += dv.w * (float)wfr[((HH)*8+mi8)>>1][3 + 4*(mi8&1)];            \
        *(float4*)&trbZ[wid][lm][mi*16 + 4*lh] = make_float4(acc[0],acc[1],acc[2],acc[3]); \
      }                                                                         \
      __builtin_amdgcn_wave_barrier();                                          \
      _Pragma("unroll")                                                         \
      for (int j = 0; j < 4; ++j){                                              \
        const int r_ = j*4 + (l >> 4), c16 = l & 15;                            \
        const float4 v = *(const float4*)&trbZ[wid][r_][4*c16];                 \
        *(float4*)&zbase[(size_t)r_*D_ + g*64 + 4*c16] = v;                     \
      }                                                                         \
      __builtin_amdgcn_wave_barrier();                                          \
    } }

#define YLOOP(COFF, NMY)                                                        \
  { float* yrow = outY + ((size_t)t*B_ + col)*NO_ + (COFF);                     \
    _Pragma("unroll")                                                           \
    for (int my = 0; my < (NMY); ++my){                                         \
      f32x4 acc = {0.f,0.f,0.f,0.f};                                            \
      _Pragma("unroll")                                                         \
      for (int kc = 0; kc < 8; ++kc){                                           \
        const bf16x8 af = *(const bf16x8*)&AfYhL[((my*10+kc)*64 + l)*8];        \
        acc = mfma16(af, wfr[kc], acc);                                         \
      }                                                                         \
      { const bf16x8 af8 = *(const bf16x8*)&AfYhL[((my*10+8)*64 + l)*8];        \
        const bf16x8 af9 = *(const bf16x8*)&AfYhL[((my*10+9)*64 + l)*8];        \
        acc = mfma16(af8, uf0, acc); acc = mfma16(af9, uf1, acc); }             \
      *(float4*)&yrow[my*16 + 4*lh] = make_float4(acc[0],acc[1],acc[2],acc[3]); \
    } }

  #pragma unroll
  for (int cc = 0; cc < 4; ++cc){
    const int ch = chq*4 + cc;

    // boundary w (slot ch; scanB already combined)
    float w[64];
    #pragma unroll
    for (int kc = 0; kc < 8; ++kc)
      #pragma unroll
      for (int hh = 0; hh < 2; ++hh){
        const int i = 32*kc + 16*hh + 4*lh;
        const ushort4 wu = *(const ushort4*)(Wchk + ((size_t)ch*B_ + col)*D_ + i);
        const int e = 8*kc + 4*hh;
        w[e+0]=bf2f(wu.x); w[e+1]=bf2f(wu.y); w[e+2]=bf2f(wu.z); w[e+3]=bf2f(wu.w);
      }

    // u prefetch for this ch's first step
    float4 ua, ub, uc;
    {
      const float* Ut = Ucol + (size_t)(ch*8)*TS;
      ua = *(const float4*)&Ut[4*lh]; ub = *(const float4*)&Ut[16+4*lh]; uc = *(const float4*)&Ut[32+4*lh];
    }

    #pragma unroll 1
    for (int s = 0; s < 8; ++s){
      const int t = ch*8 + s;
      bf16x8 uf0, uf1;
      {
        union { ushort_t us[8]; bf16x8 v; } cv;
        cv.us[0]=f2bf(ua.x); cv.us[1]=f2bf(ua.y); cv.us[2]=f2bf(ua.z); cv.us[3]=f2bf(ua.w);
        cv.us[4]=f2bf(ub.x); cv.us[5]=f2bf(ub.y); cv.us[6]=f2bf(ub.z); cv.us[7]=f2bf(ub.w);
        uf0 = cv.v;
        cv.us[0]=f2bf(uc.x); cv.us[1]=f2bf(uc.y); cv.us[2]=f2bf(uc.z); cv.us[3]=f2bf(uc.w);
        cv.us[4]=0; cv.us[5]=0; cv.us[6]=0; cv.us[7]=0;
        uf1 = cv.v;
      }
      if (s < 7){
        const float* Ut = Ucol + (size_t)(t+1)*TS;
        ua = *(const float4*)&Ut[4*lh]; ub = *(const float4*)&Ut[16+4*lh]; uc = *(const float4*)&Ut[32+4*lh];
      }
      #pragma unroll
      for (int it = 0; it < 16; ++it){
        const bf16x8 a0 = *(const bf16x8*)&LwsL[((it*2+0)*64 + l)*8];
        const bf16x8 a1 = *(const bf16x8*)&LwsL[((it*2+1)*64 + l)*8];
        const float4 lv = *(const float4*)&lamL[32*(it>>1) + 16*(it&1) + 4*lh];
        f32x4 acc = {0.f,0.f,0.f,0.f};
        acc = mfma16(a0, uf0, acc);
        acc = mfma16(a1, uf1, acc);
        const int e0 = 8*(it>>1) + 4*(it&1);
        w[e0+0] = lv.x*w[e0+0] + acc[0];
        w[e0+1] = lv.y*w[e0+1] + acc[1];
        w[e0+2] = lv.z*w[e0+2] + acc[2];
        w[e0+3] = lv.w*w[e0+3] + acc[3];
      }
      bf16x8 wfr[8];
      #pragma unroll
      for (int kc = 0; kc < 8; ++kc){
        union { ushort_t us[8]; bf16x8 v; } cv;
        #pragma unroll
        for (int j = 0; j < 8; ++j) cv.us[j] = f2bf(w[8*kc + j]);
        wfr[kc] = cv.v;
      }
      if (h == 0){
        ZLOOP(0);
        YLOOP(0, 4);
      } else {
        ZLOOP(1);
        YLOOP(64, 1);
      }
    }
  }
#undef ZLOOP
#undef YLOOP
}

// ---------------- launcher: 7 launches ----------------
extern "C" void kernel_launch(void* const* d_in, const int* in_sizes, int n_in,
                              void* d_out, int out_size, void* d_ws, size_t ws_size,
                              hipStream_t stream){
  const float* z0  = (const float*)d_in[0];
  const float* dt  = (const float*)d_in[2];
  const float* U   = (const float*)d_in[3];
  const float* eig = (const float*)d_in[4];
  const float* V   = (const float*)d_in[5];
  const float* L   = (const float*)d_in[6];
  const float* C   = (const float*)d_in[7];
  const float* Dm  = (const float*)d_in[8];
  float* outZ = (float*)d_out;
  float* outY = outZ + (size_t)T_*B_*D_;

  char* ws = (char*)d_ws;
  float* Wm    = (float*)(ws + 0);        // W = V^2
  float* V3m   = (float*)(ws + 262144);   // V^3
  float* VinvT = (float*)(ws + 524288);   // k3 output
  float* Lw    = (float*)(ws + 786432);
  float* Cw    = (float*)(ws + 835584);
  float* lam   = (float*)(ws + 917504);
  float* dVd   = (float*)(ws + 918528);
  ushort_t* Af   = (ushort_t*)(ws + 919552);
  ushort_t* Lws  = (ushort_t*)(ws + 1134592);
  ushort_t* Wchk = (ushort_t*)(ws + 1167360);
  // V4 parks in Wchk slot-1 space: dead after k3; scanA overwrites later (stream-ordered).
  float* V4m   = (float*)(ws + 1167360 + (size_t)B_*D_*2);
  if (ws_size < 17944576u) return;

  k1     <<<337,256,0,stream>>>(V, eig, C, Wm, Cw, lam, dVd);
  k2     <<<512,256,0,stream>>>(V, Wm, V3m, V4m);
  k3     <<<256,256,0,stream>>>(V, Wm, V3m, V4m, L, dt, VinvT, Lw);
  k_prep2<<<342,256,0,stream>>>(z0, VinvT, Lw, V, Cw, Dm, dt, Wchk, Lws, Af);
  k_scanA<<<1920,256,0,stream>>>(U, Lws, lam, Wchk);
  k_scanB<<<128,256,0,stream>>>(lam, Wchk);
  k_fused<<<256,256,0,stream>>>(U, Af, Lws, lam, dVd, Wchk, outZ, outY);
}